// Round 3
// baseline (520.056 us; speedup 1.0000x reference)
//
#include <hip/hip_runtime.h>
#include <hip/hip_bf16.h>
#include <math.h>

#define TS 2048   // sequence length T
#define KD 1024   // model dim K
#define NH 16     // heads
#define SD 64     // head dim
#define MB 4096   // B*T rows
#define LOG2E 1.4426950408889634f

typedef __attribute__((ext_vector_type(8))) short bf16x8;   // 8 bf16 (4 VGPRs)
typedef __attribute__((ext_vector_type(4))) short bf16x4;   // 4 bf16 (2 VGPRs)
typedef __attribute__((ext_vector_type(4))) float f32x4;    // MFMA accumulator
typedef unsigned short ushort_t;

#define MFMA32(a, b, c) __builtin_amdgcn_mfma_f32_16x16x32_bf16(a, b, c, 0, 0, 0)

union frag8 { bf16x8 v8; bf16x4 h[2]; };

__device__ __forceinline__ ushort_t f2bf_rn(float f) {
    union { __hip_bfloat16 h; ushort_t u; } c;
    c.h = __float2bfloat16(f);
    return c.u;
}
__device__ __forceinline__ float bf2f(ushort_t u) {
    union { unsigned u; float f; } v; v.u = ((unsigned)u) << 16;
    return v.f;
}
__device__ __forceinline__ ushort4 pk4_bf(float a, float b, float c, float d) {
    union { __hip_bfloat162 h; ushort2 u; } x, y;
    x.h = __float22bfloat162_rn(make_float2(a, b));
    y.h = __float22bfloat162_rn(make_float2(c, d));
    return make_ushort4(x.u.x, x.u.y, y.u.x, y.u.y);
}
// async global -> LDS, 16 B per lane; lds ptr must be wave-uniform
__device__ __forceinline__ void gload_lds16(const void* g, void* l) {
    __builtin_amdgcn_global_load_lds(
        (const __attribute__((address_space(1))) unsigned int*)g,
        (__attribute__((address_space(3))) unsigned int*)l, 16, 0, 0);
}

// ---------------------------------------------------------------------------
// conv_all: z=0: x -> XH,XL (hi/lo); z=1: Wq*log2e -> hi/lo (folds exp->exp2);
// z=2: Wk -> hi/lo; z=3: Wv -> hi; z=4: Wu -> hi.
// ---------------------------------------------------------------------------
__global__ __launch_bounds__(256)
void conv_all(const float* __restrict__ x, const float* __restrict__ wq,
              const float* __restrict__ wk, const float* __restrict__ wv,
              const float* __restrict__ wu,
              ushort_t* XH, ushort_t* XL, ushort_t* WqH, ushort_t* WqL,
              ushort_t* WkH, ushort_t* WkL, ushort_t* WvH, ushort_t* WuH)
{
    int z = blockIdx.y;
    const float* src; ushort_t* H; ushort_t* L = nullptr; int nblk;
    switch (z) {
        case 0:  src = x;  H = XH;  L = XL;  nblk = 4096; break;
        case 1:  src = wq; H = WqH; L = WqL; nblk = 1024; break;
        case 2:  src = wk; H = WkH; L = WkL; nblk = 1024; break;
        case 3:  src = wv; H = WvH;          nblk = 1024; break;
        default: src = wu; H = WuH;          nblk = 1024; break;
    }
    if ((int)blockIdx.x >= nblk) return;
    int idx = blockIdx.x * 256 + threadIdx.x;      // float4 index
    float4 v = ((const float4*)src)[idx];
    if (z == 1) { v.x *= LOG2E; v.y *= LOG2E; v.z *= LOG2E; v.w *= LOG2E; }
    ushort_t h0 = f2bf_rn(v.x), h1 = f2bf_rn(v.y);
    ushort_t h2 = f2bf_rn(v.z), h3 = f2bf_rn(v.w);
    ((ushort4*)H)[idx] = make_ushort4(h0, h1, h2, h3);
    if (L) {
        ushort_t l0 = f2bf_rn(v.x - bf2f(h0)), l1 = f2bf_rn(v.y - bf2f(h1));
        ushort_t l2 = f2bf_rn(v.z - bf2f(h2)), l3 = f2bf_rn(v.w - bf2f(h3));
        ((ushort4*)L)[idx] = make_ushort4(l0, l1, l2, l3);
    }
}

// ---------------------------------------------------------------------------
// MFMA GEMM: C = A @ W^T. m97 geometry: 128x128 tile, BK=32, 4 waves (2x2),
// 64x64 per wave, acc[4][4]. (unchanged from round 1)
// ---------------------------------------------------------------------------
__global__ __launch_bounds__(256)
void gemm_bf16(const ushort_t* __restrict__ Ah, const ushort_t* __restrict__ Al,
               const ushort_t* __restrict__ Bqh, const ushort_t* __restrict__ Bql,
               const ushort_t* __restrict__ Bkh, const ushort_t* __restrict__ Bkl,
               const ushort_t* __restrict__ Bvh, const ushort_t* __restrict__ Buh,
               ushort_t* __restrict__ OQh, ushort_t* __restrict__ OQl,
               ushort_t* __restrict__ OKh, ushort_t* __restrict__ OKl,
               ushort_t* __restrict__ OVt, float* __restrict__ OF,
               const float* __restrict__ bias, int epi_base)
{
    const int epi = epi_base + blockIdx.z;
    const ushort_t* Bh; const ushort_t* Bl = nullptr;
    if      (epi == 0) { Bh = Bqh; Bl = Bql; }
    else if (epi == 1) { Bh = Bkh; Bl = Bkl; }
    else if (epi == 2) { Bh = Bvh; }
    else               { Bh = Buh; }
    const bool terms3 = (epi < 2);

    __shared__ ushort_t sAh[128 * 32];   // 8 KB each, 32 KB total
    __shared__ ushort_t sAl[128 * 32];
    __shared__ ushort_t sBh[128 * 32];
    __shared__ ushort_t sBl[128 * 32];

    const int tid = threadIdx.x;
    const int wave = tid >> 6, lane = tid & 63;
    const int col = lane & 15, quad = lane >> 4;
    const int wm = wave >> 1, wn = wave & 1;
    const int m0 = blockIdx.y * 128, n0 = blockIdx.x * 128;

    f32x4 acc[4][4];
#pragma unroll
    for (int i = 0; i < 4; ++i)
#pragma unroll
        for (int j = 0; j < 4; ++j) acc[i][j] = (f32x4){0.f, 0.f, 0.f, 0.f};

    for (int k0 = 0; k0 < KD; k0 += 32) {
#pragma unroll
        for (int half = 0; half < 2; ++half) {
            int s   = half * 256 + wave * 64 + lane;
            int row = s >> 2, k8 = s & 3;
            int lo  = (half * 256 + wave * 64) * 8;   // wave-uniform ushort off
            gload_lds16(Ah + (size_t)(m0 + row) * KD + k0 + k8 * 8, sAh + lo);
            gload_lds16(Bh + (size_t)(n0 + row) * KD + k0 + k8 * 8, sBh + lo);
            if (terms3) {
                gload_lds16(Al + (size_t)(m0 + row) * KD + k0 + k8 * 8, sAl + lo);
                gload_lds16(Bl + (size_t)(n0 + row) * KD + k0 + k8 * 8, sBl + lo);
            }
        }
        __syncthreads();

        bf16x8 fah[4], fal[4], fbh[4], fbl[4];
#pragma unroll
        for (int j = 0; j < 4; ++j) {
            int ra = (wm * 64 + j * 16 + col) * 32 + quad * 8;
            int rb = (wn * 64 + j * 16 + col) * 32 + quad * 8;
            fah[j] = *(const bf16x8*)&sAh[ra];
            fbh[j] = *(const bf16x8*)&sBh[rb];
            if (terms3) {
                fal[j] = *(const bf16x8*)&sAl[ra];
                fbl[j] = *(const bf16x8*)&sBl[rb];
            }
        }
#pragma unroll
        for (int i = 0; i < 4; ++i) {
            if (terms3) {
#pragma unroll
                for (int j = 0; j < 4; ++j) {
                    acc[i][j] = MFMA32(fah[i], fbh[j], acc[i][j]);
                    acc[i][j] = MFMA32(fah[i], fbl[j], acc[i][j]);
                    acc[i][j] = MFMA32(fal[i], fbh[j], acc[i][j]);
                }
            } else {
#pragma unroll
                for (int j = 0; j < 4; ++j)
                    acc[i][j] = MFMA32(fah[i], fbh[j], acc[i][j]);
            }
        }
        __syncthreads();
    }

    // ---- epilogues (C/D: row m = quad*4+reg, col n = lane&15) ----
    if (epi <= 1) {
        ushort_t* OH = (epi == 0) ? OQh : OKh;
        ushort_t* OL = (epi == 0) ? OQl : OKl;
#pragma unroll
        for (int i = 0; i < 4; ++i) {
            int m = m0 + wm * 64 + i * 16 + quad * 4;
#pragma unroll
            for (int j = 0; j < 4; ++j) {
                int n = n0 + wn * 64 + j * 16 + col;
#pragma unroll
                for (int r = 0; r < 4; ++r) {
                    float v = acc[i][j][r];
                    ushort_t hv = f2bf_rn(v);
                    size_t off = (size_t)(m + r) * KD + n;
                    OH[off] = hv;
                    OL[off] = f2bf_rn(v - bf2f(hv));
                }
            }
        }
    } else if (epi == 2) {
#pragma unroll
        for (int i = 0; i < 4; ++i) {
            int m = m0 + wm * 64 + i * 16 + quad * 4;
            int bb = m >> 11, t = m & (TS - 1);
#pragma unroll
            for (int j = 0; j < 4; ++j) {
                int n = n0 + wn * 64 + j * 16 + col;
                int hh = n >> 6, d = n & 63;
                ushort4 pk = pk4_bf(acc[i][j][0], acc[i][j][1], acc[i][j][2], acc[i][j][3]);
                *(ushort4*)(OVt + ((size_t)(bb * NH + hh) * SD + d) * TS + t) = pk;
            }
        }
    } else {
#pragma unroll
        for (int i = 0; i < 4; ++i) {
            int m = m0 + wm * 64 + i * 16 + quad * 4;
#pragma unroll
            for (int j = 0; j < 4; ++j) {
                int n = n0 + wn * 64 + j * 16 + col;
                float bj = bias[n];
#pragma unroll
                for (int r = 0; r < 4; ++r)
                    OF[(size_t)(m + r) * KD + n] = acc[i][j][r] + bj;
            }
        }
    }
}

// ---------------------------------------------------------------------------
// MFMA flash attention — round-0 sync structure (single-buffer staging, the
// measured-best; dbuf reverted) + REGISTER DIET to lift occupancy 2->3
// blocks/CU (unified VGPR+AGPR file: old total ~188/wave -> 2 waves/SIMD):
//   * Q-lo fragments (32 VGPRs, held all kernel) -> 8 KB XOR-swizzled LDS
//     tile staged once in the prologue; read per kt as ds_read_b128.
//     swizzle: byte = row*128 + d16*16, swz ^= (row&7)<<4 (same involution on
//     write and read; residual 2-way bank aliasing = free per m136).
//   * gp[]/ld[] pointer arrays (12 regs) -> two 32-bit lane offsets aK/aV +
//     uniform scalar strides recomputed per kt.
//   __launch_bounds__(256,3) forces regalloc to fit 3 waves/SIMD.
// ---------------------------------------------------------------------------
__global__ __launch_bounds__(256, 3)
void attn_mfma(const ushort_t* __restrict__ QH, const ushort_t* __restrict__ QL,
               const ushort_t* __restrict__ KH, const ushort_t* __restrict__ KL,
               const ushort_t* __restrict__ VT, const int* __restrict__ mask,
               ushort_t* __restrict__ YH)
{
    const int bh = blockIdx.x;       // 0..31  (fastest dim -> pins XCD = bh%8)
    const int qt = blockIdx.y;       // 0..31
    const int h  = bh & (NH - 1);
    const int b  = bh >> 4;

    const int tid  = threadIdx.x;
    const int wave = tid >> 6;
    const int lane = tid & 63;
    const int col  = lane & 15;
    const int quad = lane >> 4;

    // 32 KB: K hi/lo + V^T staging (24 KB, single-buffered) + Q-lo tile (8 KB)
    __shared__ ushort_t smem[16384];
    ushort_t* sKH = smem;                // [key][d] swizzled, 8 KB
    ushort_t* sKL = smem + 4096;
    ushort_t* sVT = smem + 8192;         // [d][key] swizzled, 8 KB
    ushort_t* sQL = smem + 12288;        // Q-lo [qrow][d] swizzled, 8 KB
    __shared__ float lred[4][64];

    // ---- Q-hi fragments in registers; Q-lo staged to swizzled LDS ----
    bf16x8 bqh[4][2];
#pragma unroll
    for (int qf = 0; qf < 4; ++qf) {
        size_t qrow = (size_t)(b * TS + qt * 64 + qf * 16 + col) * KD + h * SD;
#pragma unroll
        for (int c = 0; c < 2; ++c)
            bqh[qf][c] = *(const bf16x8*)(QH + qrow + c * 32 + quad * 8);
    }
    {
        int s = tid;                     // 512 slots of 16 B, 2 per thread
#pragma unroll
        for (int p = 0; p < 2; ++p, s += 256) {
            int row = s >> 3, dblk = s & 7;
            bf16x8 v = *(const bf16x8*)(QL + (size_t)(b * TS + qt * 64 + row) * KD +
                                        h * SD + dblk * 8);
            *(bf16x8*)((char*)sQL + ((row * 128 + dblk * 16) ^ ((row & 7) << 4))) = v;
        }
    }

    // ---- slim staging addressing: lane offsets + uniform strides ----
    const int l8 = lane >> 3, l7 = lane & 7;
    const int gs = (l7 ^ l8) * 8;                       // XOR-swizzled 16B slot
    const int aK = (wave * 8 + l8) * KD + gs;           // K-chunk lane offset
    const int aV = (bh * SD + wave * 8 + l8) * TS + gs; // V-chunk lane offset
    size_t kOff = (size_t)b * TS * KD + h * SD;         // uniform, += 64*KD/kt
    int    vOff = 0;                                    // uniform, += 64/kt
    const int* mp = mask + b * TS + wave * 16 + quad * 4;

    float lp[4] = {0.f, 0.f, 0.f, 0.f};
    f32x4 O[4][4];                        // [dt][qf], O^T: row=d, col=q
#pragma unroll
    for (int dt = 0; dt < 4; ++dt)
#pragma unroll
        for (int qf = 0; qf < 4; ++qf) O[dt][qf] = (f32x4){0.f, 0.f, 0.f, 0.f};

    frag8 av[4], bp4[4];
#pragma unroll
    for (int i = 0; i < 4; ++i) {
        av[i].v8  = (bf16x8){0, 0, 0, 0, 0, 0, 0, 0};
        bp4[i].v8 = (bf16x8){0, 0, 0, 0, 0, 0, 0, 0};
    }

    for (int kt = 0; kt < TS / 64; ++kt) {
        gload_lds16(KH + kOff + aK,           sKH + wave * 512);
        gload_lds16(KH + kOff + aK + 32 * KD, sKH + (wave + 4) * 512);
        gload_lds16(KL + kOff + aK,           sKL + wave * 512);
        gload_lds16(KL + kOff + aK + 32 * KD, sKL + (wave + 4) * 512);
        gload_lds16(VT + aV + vOff,           sVT + wave * 512);
        gload_lds16(VT + aV + vOff + 32 * TS, sVT + (wave + 4) * 512);
        int4 mv = *(const int4*)mp;
        mp += 64;
        kOff += 64 * KD;
        vOff += 64;
        __syncthreads();

        // masked keys: S starts at -inf -> exp2 gives exactly 0
        f32x4 sinit;
        sinit[0] = mv.x ? 0.f : -INFINITY;
        sinit[1] = mv.y ? 0.f : -INFINITY;
        sinit[2] = mv.z ? 0.f : -INFINITY;
        sinit[3] = mv.w ? 0.f : -INFINITY;

        // ---- K / V fragments for this wave's 16-key strip ----
        bf16x8 akh[2], akl[2];
#pragma unroll
        for (int c = 0; c < 2; ++c) {
            int sl = (c * 4 + quad) ^ (col & 7);
            akh[c] = *(const bf16x8*)&sKH[((wave * 16 + col) * 8 + sl) * 8];
            akl[c] = *(const bf16x8*)&sKL[((wave * 16 + col) * 8 + sl) * 8];
        }
#pragma unroll
        for (int dt = 0; dt < 4; ++dt) {
            int sl = (wave * 2 + (quad >> 1)) ^ (col & 7);
            av[dt].h[0] = *(const bf16x4*)&sVT[((dt * 16 + col) * 8 + sl) * 8 + (quad & 1) * 4];
        }

        // ---- S^T strips (hi/lo 3-term, 2 indep chains) + exp2 + pack P ----
#pragma unroll
        for (int qf = 0; qf < 4; ++qf) {
            int qrow  = qf * 16 + col;
            int qbase = qrow * 128;
            int qsw   = (qrow & 7) << 4;
            bf16x8 bql0 = *(const bf16x8*)((const char*)sQL + qbase + ((quad * 16) ^ qsw));
            bf16x8 bql1 = *(const bf16x8*)((const char*)sQL + qbase + ((64 + quad * 16) ^ qsw));
            f32x4 s1 = sinit;
            f32x4 s2 = (f32x4){0.f, 0.f, 0.f, 0.f};
            s1 = MFMA32(akh[0], bqh[qf][0], s1);
            s2 = MFMA32(akl[0], bqh[qf][0], s2);
            s2 = MFMA32(akh[0], bql0, s2);
            s1 = MFMA32(akh[1], bqh[qf][1], s1);
            s2 = MFMA32(akl[1], bqh[qf][1], s2);
            s2 = MFMA32(akh[1], bql1, s2);
            float p0 = exp2f(s1[0] + s2[0]);
            float p1 = exp2f(s1[1] + s2[1]);
            float p2 = exp2f(s1[2] + s2[2]);
            float p3 = exp2f(s1[3] + s2[3]);
            lp[qf] += (p0 + p1) + (p2 + p3);
            union { ushort4 u4; bf16x4 v4; } pk;
            pk.u4 = pk4_bf(p0, p1, p2, p3);
            bp4[qf].h[0] = pk.v4;
        }

        // ---- O^T += V^T x P^T (zero-padded K=32 MFMA, P direct from regs) ----
#pragma unroll
        for (int dt = 0; dt < 4; ++dt)
#pragma unroll
            for (int qf = 0; qf < 4; ++qf)
                O[dt][qf] = MFMA32(av[dt].v8, bp4[qf].v8, O[dt][qf]);

        __syncthreads();
    }

    // ---- l: reduce over quads, publish per wave ----
#pragma unroll
    for (int qf = 0; qf < 4; ++qf) {
        float v = lp[qf];
        v += __shfl_xor(v, 16);
        v += __shfl_xor(v, 32);
        if (lane < 16) lred[wave][qf * 16 + lane] = v;
    }

    // ---- staged O-reduce through 16 KB of LDS (3 rounds) ----
    float* Of = (float*)smem;
#pragma unroll
    for (int w = 1; w < 4; ++w) {
        __syncthreads();
        if (wave == w) {
#pragma unroll
            for (int dt = 0; dt < 4; ++dt)
#pragma unroll
                for (int qf = 0; qf < 4; ++qf)
                    *(f32x4*)&Of[((dt * 4 + qf) * 64 + lane) * 4] = O[dt][qf];
        }
        __syncthreads();
        if (wave == 0) {
#pragma unroll
            for (int dt = 0; dt < 4; ++dt)
#pragma unroll
                for (int qf = 0; qf < 4; ++qf)
                    O[dt][qf] += *(const f32x4*)&Of[((dt * 4 + qf) * 64 + lane) * 4];
        }
    }
    if (wave == 0) {
        float linv[4];
#pragma unroll
        for (int qf = 0; qf < 4; ++qf) {
            int q = qf * 16 + col;
            linv[qf] = 1.f / (lred[0][q] + lred[1][q] + lred[2][q] + lred[3][q]);
        }
#pragma unroll
        for (int dt = 0; dt < 4; ++dt)
#pragma unroll
            for (int qf = 0; qf < 4; ++qf) {
                ushort4 pk = pk4_bf(O[dt][qf][0] * linv[qf], O[dt][qf][1] * linv[qf],
                                    O[dt][qf][2] * linv[qf], O[dt][qf][3] * linv[qf]);
                *(ushort4*)(YH + (size_t)(b * TS + qt * 64 + qf * 16 + col) * KD +
                            h * SD + dt * 16 + quad * 4) = pk;
            }
    }
}

// ---------------------------------------------------------------------------
extern "C" void kernel_launch(void* const* d_in, const int* in_sizes, int n_in,
                              void* d_out, int out_size, void* d_ws, size_t ws_size,
                              hipStream_t stream) {
    const float* x    = (const float*)d_in[0];
    const int*   mask = (const int*)d_in[1];
    const float* Wk   = (const float*)d_in[2];
    const float* Wq   = (const float*)d_in[3];
    const float* Wv   = (const float*)d_in[4];
    const float* Wu   = (const float*)d_in[5];
    const float* bu   = (const float*)d_in[6];
    float* out = (float*)d_out;

    char* w = (char*)d_ws;
    const size_t M1 = (size_t)1 << 20;
    // workspace plan (60 MB peak; VT lives in d_out until the U gemm):
    ushort_t* XH  = (ushort_t*)(w);              // [0,8M)
    ushort_t* XL  = (ushort_t*)(w + 8  * M1);    // [8,16M)
    ushort_t* WqH = (ushort_t*)(w + 16 * M1);
    ushort_t* WqL = (ushort_t*)(w + 18 * M1);
    ushort_t* WkH = (ushort_t*)(w + 20 * M1);
    ushort_t* WkL = (ushort_t*)(w + 22 * M1);
    ushort_t* WvH = (ushort_t*)(w + 24 * M1);    // [24,26M)
    ushort_t* QHb = (ushort_t*)(w + 26 * M1);    // [26,34M)
    ushort_t* QLb = (ushort_t*)(w + 34 * M1);
    ushort_t* KHb = (ushort_t*)(w + 42 * M1);
    ushort_t* KLb = (ushort_t*)(w + 50 * M1);    // ..58M
    ushort_t* WuH = (ushort_t*)(w + 58 * M1);    // [58,60M)
    ushort_t* VTb = (ushort_t*)d_out;            // 8 MB scratch in d_out
    ushort_t* YHb = (ushort_t*)(w);              // over XH (dead after QKV)

    dim3 blk(256);
    conv_all<<<dim3(4096, 5), blk, 0, stream>>>(x, Wq, Wk, Wv, Wu,
                                                XH, XL, WqH, WqL, WkH, WkL, WvH, WuH);
    // fused Q,K,V projections: 128x128 tiles -> 32x8x3 = 768 blocks = 3/CU
    gemm_bf16<<<dim3(8, 32, 3), blk, 0, stream>>>(XH, XL, WqH, WqL, WkH, WkL, WvH, WuH,
                                                  QHb, QLb, KHb, KLb, VTb, nullptr,
                                                  nullptr, 0);
    // attention: grid(bh, qt) so each (b,h)'s 32 blocks share one XCD's L2
    attn_mfma<<<dim3(NH * 2, 32), blk, 0, stream>>>(QHb, QLb, KHb, KLb, VTb, mask, YHb);
    // output projection + bias: 128x128 tiles -> 256 blocks
    gemm_bf16<<<dim3(8, 32, 1), blk, 0, stream>>>(YHb, nullptr, WqH, WqL, WkH, WkL, WvH, WuH,
                                                  nullptr, nullptr, nullptr, nullptr, nullptr,
                                                  out, bu, 3);
}

// Round 4
// 296.823 us; speedup vs baseline: 1.7521x; 1.7521x over previous
//
#include <hip/hip_runtime.h>
#include <hip/hip_bf16.h>
#include <math.h>

#define TS 2048   // sequence length T
#define KD 1024   // model dim K
#define NH 16     // heads
#define SD 64     // head dim
#define MB 4096   // B*T rows
#define LOG2E 1.4426950408889634f

typedef __attribute__((ext_vector_type(8))) short bf16x8;   // 8 bf16 (4 VGPRs)
typedef __attribute__((ext_vector_type(4))) short bf16x4;   // 4 bf16 (2 VGPRs)
typedef __attribute__((ext_vector_type(4))) float f32x4;    // MFMA accumulator
typedef unsigned short ushort_t;

#define MFMA32(a, b, c) __builtin_amdgcn_mfma_f32_16x16x32_bf16(a, b, c, 0, 0, 0)

union frag8 { bf16x8 v8; bf16x4 h[2]; };

__device__ __forceinline__ ushort_t f2bf_rn(float f) {
    union { __hip_bfloat16 h; ushort_t u; } c;
    c.h = __float2bfloat16(f);
    return c.u;
}
__device__ __forceinline__ float bf2f(ushort_t u) {
    union { unsigned u; float f; } v; v.u = ((unsigned)u) << 16;
    return v.f;
}
__device__ __forceinline__ ushort4 pk4_bf(float a, float b, float c, float d) {
    union { __hip_bfloat162 h; ushort2 u; } x, y;
    x.h = __float22bfloat162_rn(make_float2(a, b));
    y.h = __float22bfloat162_rn(make_float2(c, d));
    return make_ushort4(x.u.x, x.u.y, y.u.x, y.u.y);
}
// hardware exp2: single v_exp_f32 (<=1 ulp; P is rounded to bf16 right after,
// so the OCML denormal/range handling is pure overhead). exp2(-inf)=0 exactly,
// preserving the mask semantics.
__device__ __forceinline__ float fexp2(float x) {
#if __has_builtin(__builtin_amdgcn_exp2f)
    return __builtin_amdgcn_exp2f(x);
#else
    return exp2f(x);
#endif
}
// async global -> LDS, 16 B per lane; lds ptr must be wave-uniform
__device__ __forceinline__ void gload_lds16(const void* g, void* l) {
    __builtin_amdgcn_global_load_lds(
        (const __attribute__((address_space(1))) unsigned int*)g,
        (__attribute__((address_space(3))) unsigned int*)l, 16, 0, 0);
}

// ---------------------------------------------------------------------------
// conv_all: z=0: x -> XH,XL (hi/lo); z=1: Wq*log2e -> hi/lo (folds exp->exp2);
// z=2: Wk -> hi/lo; z=3: Wv -> hi; z=4: Wu -> hi.
// ---------------------------------------------------------------------------
__global__ __launch_bounds__(256)
void conv_all(const float* __restrict__ x, const float* __restrict__ wq,
              const float* __restrict__ wk, const float* __restrict__ wv,
              const float* __restrict__ wu,
              ushort_t* XH, ushort_t* XL, ushort_t* WqH, ushort_t* WqL,
              ushort_t* WkH, ushort_t* WkL, ushort_t* WvH, ushort_t* WuH)
{
    int z = blockIdx.y;
    const float* src; ushort_t* H; ushort_t* L = nullptr; int nblk;
    switch (z) {
        case 0:  src = x;  H = XH;  L = XL;  nblk = 4096; break;
        case 1:  src = wq; H = WqH; L = WqL; nblk = 1024; break;
        case 2:  src = wk; H = WkH; L = WkL; nblk = 1024; break;
        case 3:  src = wv; H = WvH;          nblk = 1024; break;
        default: src = wu; H = WuH;          nblk = 1024; break;
    }
    if ((int)blockIdx.x >= nblk) return;
    int idx = blockIdx.x * 256 + threadIdx.x;      // float4 index
    float4 v = ((const float4*)src)[idx];
    if (z == 1) { v.x *= LOG2E; v.y *= LOG2E; v.z *= LOG2E; v.w *= LOG2E; }
    ushort_t h0 = f2bf_rn(v.x), h1 = f2bf_rn(v.y);
    ushort_t h2 = f2bf_rn(v.z), h3 = f2bf_rn(v.w);
    ((ushort4*)H)[idx] = make_ushort4(h0, h1, h2, h3);
    if (L) {
        ushort_t l0 = f2bf_rn(v.x - bf2f(h0)), l1 = f2bf_rn(v.y - bf2f(h1));
        ushort_t l2 = f2bf_rn(v.z - bf2f(h2)), l3 = f2bf_rn(v.w - bf2f(h3));
        ((ushort4*)L)[idx] = make_ushort4(l0, l1, l2, l3);
    }
}

// ---------------------------------------------------------------------------
// MFMA GEMM: C = A @ W^T. m97 geometry: 128x128 tile, BK=32, 4 waves (2x2),
// 64x64 per wave, acc[4][4]. (unchanged from round 1 — measured neutral vs
// round 0, kept for the better MFMA:ds_read ratio)
// ---------------------------------------------------------------------------
__global__ __launch_bounds__(256)
void gemm_bf16(const ushort_t* __restrict__ Ah, const ushort_t* __restrict__ Al,
               const ushort_t* __restrict__ Bqh, const ushort_t* __restrict__ Bql,
               const ushort_t* __restrict__ Bkh, const ushort_t* __restrict__ Bkl,
               const ushort_t* __restrict__ Bvh, const ushort_t* __restrict__ Buh,
               ushort_t* __restrict__ OQh, ushort_t* __restrict__ OQl,
               ushort_t* __restrict__ OKh, ushort_t* __restrict__ OKl,
               ushort_t* __restrict__ OVt, float* __restrict__ OF,
               const float* __restrict__ bias, int epi_base)
{
    const int epi = epi_base + blockIdx.z;
    const ushort_t* Bh; const ushort_t* Bl = nullptr;
    if      (epi == 0) { Bh = Bqh; Bl = Bql; }
    else if (epi == 1) { Bh = Bkh; Bl = Bkl; }
    else if (epi == 2) { Bh = Bvh; }
    else               { Bh = Buh; }
    const bool terms3 = (epi < 2);

    __shared__ ushort_t sAh[128 * 32];   // 8 KB each, 32 KB total
    __shared__ ushort_t sAl[128 * 32];
    __shared__ ushort_t sBh[128 * 32];
    __shared__ ushort_t sBl[128 * 32];

    const int tid = threadIdx.x;
    const int wave = tid >> 6, lane = tid & 63;
    const int col = lane & 15, quad = lane >> 4;
    const int wm = wave >> 1, wn = wave & 1;
    const int m0 = blockIdx.y * 128, n0 = blockIdx.x * 128;

    f32x4 acc[4][4];
#pragma unroll
    for (int i = 0; i < 4; ++i)
#pragma unroll
        for (int j = 0; j < 4; ++j) acc[i][j] = (f32x4){0.f, 0.f, 0.f, 0.f};

    for (int k0 = 0; k0 < KD; k0 += 32) {
#pragma unroll
        for (int half = 0; half < 2; ++half) {
            int s   = half * 256 + wave * 64 + lane;
            int row = s >> 2, k8 = s & 3;
            int lo  = (half * 256 + wave * 64) * 8;   // wave-uniform ushort off
            gload_lds16(Ah + (size_t)(m0 + row) * KD + k0 + k8 * 8, sAh + lo);
            gload_lds16(Bh + (size_t)(n0 + row) * KD + k0 + k8 * 8, sBh + lo);
            if (terms3) {
                gload_lds16(Al + (size_t)(m0 + row) * KD + k0 + k8 * 8, sAl + lo);
                gload_lds16(Bl + (size_t)(n0 + row) * KD + k0 + k8 * 8, sBl + lo);
            }
        }
        __syncthreads();

        bf16x8 fah[4], fal[4], fbh[4], fbl[4];
#pragma unroll
        for (int j = 0; j < 4; ++j) {
            int ra = (wm * 64 + j * 16 + col) * 32 + quad * 8;
            int rb = (wn * 64 + j * 16 + col) * 32 + quad * 8;
            fah[j] = *(const bf16x8*)&sAh[ra];
            fbh[j] = *(const bf16x8*)&sBh[rb];
            if (terms3) {
                fal[j] = *(const bf16x8*)&sAl[ra];
                fbl[j] = *(const bf16x8*)&sBl[rb];
            }
        }
#pragma unroll
        for (int i = 0; i < 4; ++i) {
            if (terms3) {
#pragma unroll
                for (int j = 0; j < 4; ++j) {
                    acc[i][j] = MFMA32(fah[i], fbh[j], acc[i][j]);
                    acc[i][j] = MFMA32(fah[i], fbl[j], acc[i][j]);
                    acc[i][j] = MFMA32(fal[i], fbh[j], acc[i][j]);
                }
            } else {
#pragma unroll
                for (int j = 0; j < 4; ++j)
                    acc[i][j] = MFMA32(fah[i], fbh[j], acc[i][j]);
            }
        }
        __syncthreads();
    }

    // ---- epilogues (C/D: row m = quad*4+reg, col n = lane&15) ----
    if (epi <= 1) {
        ushort_t* OH = (epi == 0) ? OQh : OKh;
        ushort_t* OL = (epi == 0) ? OQl : OKl;
#pragma unroll
        for (int i = 0; i < 4; ++i) {
            int m = m0 + wm * 64 + i * 16 + quad * 4;
#pragma unroll
            for (int j = 0; j < 4; ++j) {
                int n = n0 + wn * 64 + j * 16 + col;
#pragma unroll
                for (int r = 0; r < 4; ++r) {
                    float v = acc[i][j][r];
                    ushort_t hv = f2bf_rn(v);
                    size_t off = (size_t)(m + r) * KD + n;
                    OH[off] = hv;
                    OL[off] = f2bf_rn(v - bf2f(hv));
                }
            }
        }
    } else if (epi == 2) {
#pragma unroll
        for (int i = 0; i < 4; ++i) {
            int m = m0 + wm * 64 + i * 16 + quad * 4;
            int bb = m >> 11, t = m & (TS - 1);
#pragma unroll
            for (int j = 0; j < 4; ++j) {
                int n = n0 + wn * 64 + j * 16 + col;
                int hh = n >> 6, d = n & 63;
                ushort4 pk = pk4_bf(acc[i][j][0], acc[i][j][1], acc[i][j][2], acc[i][j][3]);
                *(ushort4*)(OVt + ((size_t)(bb * NH + hh) * SD + d) * TS + t) = pk;
            }
        }
    } else {
#pragma unroll
        for (int i = 0; i < 4; ++i) {
            int m = m0 + wm * 64 + i * 16 + quad * 4;
#pragma unroll
            for (int j = 0; j < 4; ++j) {
                int n = n0 + wn * 64 + j * 16 + col;
                float bj = bias[n];
#pragma unroll
                for (int r = 0; r < 4; ++r)
                    OF[(size_t)(m + r) * KD + n] = acc[i][j][r] + bj;
            }
        }
    }
}

// ---------------------------------------------------------------------------
// MFMA flash attention — EXACT round-0 structure (measured best: 117.6 us;
// dbuf and reg-diet both reverted after measured regressions). Single change
// vs round 0: exp2f -> fexp2 (raw v_exp_f32) to cut the OCML exp2 VALU tail
// (VALUBusy 48% is the dominant pipe; 16 exp2 per wave per kt on the
// QK->PV critical path).
// ---------------------------------------------------------------------------
__global__ __launch_bounds__(256, 2)
void attn_mfma(const ushort_t* __restrict__ QH, const ushort_t* __restrict__ QL,
               const ushort_t* __restrict__ KH, const ushort_t* __restrict__ KL,
               const ushort_t* __restrict__ VT, const int* __restrict__ mask,
               ushort_t* __restrict__ YH)
{
    const int bh = blockIdx.x;       // 0..31  (fastest dim -> pins XCD = bh%8)
    const int qt = blockIdx.y;       // 0..31
    const int h  = bh & (NH - 1);
    const int b  = bh >> 4;

    const int tid  = threadIdx.x;
    const int wave = tid >> 6;
    const int lane = tid & 63;
    const int col  = lane & 15;
    const int quad = lane >> 4;

    __shared__ ushort_t smem[12288];     // 24 KB: staging; reused for O-reduce
    ushort_t* sKH = smem;                // [key][d] swizzled, 8 KB
    ushort_t* sKL = smem + 4096;
    ushort_t* sVT = smem + 8192;         // [d][key] swizzled, 8 KB
    __shared__ float lred[4][64];

    // ---- Q fragments, held in registers for the whole kernel ----
    bf16x8 bqh[4][2], bql[4][2];
#pragma unroll
    for (int qf = 0; qf < 4; ++qf) {
        size_t qrow = (size_t)(b * TS + qt * 64 + qf * 16 + col) * KD + h * SD;
#pragma unroll
        for (int c = 0; c < 2; ++c) {
            bqh[qf][c] = *(const bf16x8*)(QH + qrow + c * 32 + quad * 8);
            bql[qf][c] = *(const bf16x8*)(QL + qrow + c * 32 + quad * 8);
        }
    }

    // ---- hoisted staging pointers: chunk r -> {r<2: KH, r<4: KL, else VT} ----
    const int l8 = lane >> 3, l7 = lane & 7;
    const ushort_t* gp[6];
    ushort_t* ld[6];
#pragma unroll
    for (int r = 0; r < 6; ++r) {
        int cc  = (r & 1) * 4 + wave;          // chunk within its matrix (0..7)
        int row = cc * 8 + l8;                 // 0..63
        int gs  = l7 ^ (row & 7);              // XOR swizzle
        if (r < 2)      gp[r] = KH + (size_t)(b * TS + row) * KD + h * SD + gs * 8;
        else if (r < 4) gp[r] = KL + (size_t)(b * TS + row) * KD + h * SD + gs * 8;
        else            gp[r] = VT + ((size_t)bh * SD + row) * TS + gs * 8;
        ld[r] = ((r < 2) ? sKH : (r < 4) ? sKL : sVT) + cc * 512;
    }
    const int* mp = mask + b * TS + wave * 16 + quad * 4;

    float lp[4] = {0.f, 0.f, 0.f, 0.f};
    f32x4 O[4][4];                        // [dt][qf], O^T: row=d, col=q
#pragma unroll
    for (int dt = 0; dt < 4; ++dt)
#pragma unroll
        for (int qf = 0; qf < 4; ++qf) O[dt][qf] = (f32x4){0.f, 0.f, 0.f, 0.f};

    frag8 av[4], bp4[4];
#pragma unroll
    for (int i = 0; i < 4; ++i) {
        av[i].v8  = (bf16x8){0, 0, 0, 0, 0, 0, 0, 0};
        bp4[i].v8 = (bf16x8){0, 0, 0, 0, 0, 0, 0, 0};
    }

    for (int kt = 0; kt < TS / 64; ++kt) {
#pragma unroll
        for (int r = 0; r < 6; ++r) gload_lds16(gp[r], ld[r]);
        int4 mv = *(const int4*)mp;
        mp += 64;
#pragma unroll
        for (int r = 0; r < 6; ++r) gp[r] += (r < 4) ? 64 * KD : 64;
        __syncthreads();

        // masked keys: S starts at -inf -> exp2 gives exactly 0
        f32x4 sinit;
        sinit[0] = mv.x ? 0.f : -INFINITY;
        sinit[1] = mv.y ? 0.f : -INFINITY;
        sinit[2] = mv.z ? 0.f : -INFINITY;
        sinit[3] = mv.w ? 0.f : -INFINITY;

        // ---- K / V fragments for this wave's 16-key strip ----
        bf16x8 akh[2], akl[2];
#pragma unroll
        for (int c = 0; c < 2; ++c) {
            int sl = (c * 4 + quad) ^ (col & 7);
            akh[c] = *(const bf16x8*)&sKH[((wave * 16 + col) * 8 + sl) * 8];
            akl[c] = *(const bf16x8*)&sKL[((wave * 16 + col) * 8 + sl) * 8];
        }
#pragma unroll
        for (int dt = 0; dt < 4; ++dt) {
            int sl = (wave * 2 + (quad >> 1)) ^ (col & 7);
            av[dt].h[0] = *(const bf16x4*)&sVT[((dt * 16 + col) * 8 + sl) * 8 + (quad & 1) * 4];
        }

        // ---- S^T strips (hi/lo 3-term, 2 indep chains) + exp2 + pack P ----
#pragma unroll
        for (int qf = 0; qf < 4; ++qf) {
            f32x4 s1 = sinit;
            f32x4 s2 = (f32x4){0.f, 0.f, 0.f, 0.f};
            s1 = MFMA32(akh[0], bqh[qf][0], s1);
            s2 = MFMA32(akl[0], bqh[qf][0], s2);
            s2 = MFMA32(akh[0], bql[qf][0], s2);
            s1 = MFMA32(akh[1], bqh[qf][1], s1);
            s2 = MFMA32(akl[1], bqh[qf][1], s2);
            s2 = MFMA32(akh[1], bql[qf][1], s2);
            float p0 = fexp2(s1[0] + s2[0]);
            float p1 = fexp2(s1[1] + s2[1]);
            float p2 = fexp2(s1[2] + s2[2]);
            float p3 = fexp2(s1[3] + s2[3]);
            lp[qf] += (p0 + p1) + (p2 + p3);
            union { ushort4 u4; bf16x4 v4; } pk;
            pk.u4 = pk4_bf(p0, p1, p2, p3);
            bp4[qf].h[0] = pk.v4;
        }

        // ---- O^T += V^T x P^T (zero-padded K=32 MFMA, P direct from regs) ----
#pragma unroll
        for (int dt = 0; dt < 4; ++dt)
#pragma unroll
            for (int qf = 0; qf < 4; ++qf)
                O[dt][qf] = MFMA32(av[dt].v8, bp4[qf].v8, O[dt][qf]);

        __syncthreads();
    }

    // ---- l: reduce over quads, publish per wave ----
#pragma unroll
    for (int qf = 0; qf < 4; ++qf) {
        float v = lp[qf];
        v += __shfl_xor(v, 16);
        v += __shfl_xor(v, 32);
        if (lane < 16) lred[wave][qf * 16 + lane] = v;
    }

    // ---- staged O-reduce through 16 KB of LDS (3 rounds) ----
    float* Of = (float*)smem;
#pragma unroll
    for (int w = 1; w < 4; ++w) {
        __syncthreads();
        if (wave == w) {
#pragma unroll
            for (int dt = 0; dt < 4; ++dt)
#pragma unroll
                for (int qf = 0; qf < 4; ++qf)
                    *(f32x4*)&Of[((dt * 4 + qf) * 64 + lane) * 4] = O[dt][qf];
        }
        __syncthreads();
        if (wave == 0) {
#pragma unroll
            for (int dt = 0; dt < 4; ++dt)
#pragma unroll
                for (int qf = 0; qf < 4; ++qf)
                    O[dt][qf] += *(const f32x4*)&Of[((dt * 4 + qf) * 64 + lane) * 4];
        }
    }
    if (wave == 0) {
        float linv[4];
#pragma unroll
        for (int qf = 0; qf < 4; ++qf) {
            int q = qf * 16 + col;
            linv[qf] = 1.f / (lred[0][q] + lred[1][q] + lred[2][q] + lred[3][q]);
        }
#pragma unroll
        for (int dt = 0; dt < 4; ++dt)
#pragma unroll
            for (int qf = 0; qf < 4; ++qf) {
                ushort4 pk = pk4_bf(O[dt][qf][0] * linv[qf], O[dt][qf][1] * linv[qf],
                                    O[dt][qf][2] * linv[qf], O[dt][qf][3] * linv[qf]);
                *(ushort4*)(YH + (size_t)(b * TS + qt * 64 + qf * 16 + col) * KD +
                            h * SD + dt * 16 + quad * 4) = pk;
            }
    }
}

// ---------------------------------------------------------------------------
extern "C" void kernel_launch(void* const* d_in, const int* in_sizes, int n_in,
                              void* d_out, int out_size, void* d_ws, size_t ws_size,
                              hipStream_t stream) {
    const float* x    = (const float*)d_in[0];
    const int*   mask = (const int*)d_in[1];
    const float* Wk   = (const float*)d_in[2];
    const float* Wq   = (const float*)d_in[3];
    const float* Wv   = (const float*)d_in[4];
    const float* Wu   = (const float*)d_in[5];
    const float* bu   = (const float*)d_in[6];
    float* out = (float*)d_out;

    char* w = (char*)d_ws;
    const size_t M1 = (size_t)1 << 20;
    // workspace plan (60 MB peak; VT lives in d_out until the U gemm):
    ushort_t* XH  = (ushort_t*)(w);              // [0,8M)
    ushort_t* XL  = (ushort_t*)(w + 8  * M1);    // [8,16M)
    ushort_t* WqH = (ushort_t*)(w + 16 * M1);
    ushort_t* WqL = (ushort_t*)(w + 18 * M1);
    ushort_t* WkH = (ushort_t*)(w + 20 * M1);
    ushort_t* WkL = (ushort_t*)(w + 22 * M1);
    ushort_t* WvH = (ushort_t*)(w + 24 * M1);    // [24,26M)
    ushort_t* QHb = (ushort_t*)(w + 26 * M1);    // [26,34M)
    ushort_t* QLb = (ushort_t*)(w + 34 * M1);
    ushort_t* KHb = (ushort_t*)(w + 42 * M1);
    ushort_t* KLb = (ushort_t*)(w + 50 * M1);    // ..58M
    ushort_t* WuH = (ushort_t*)(w + 58 * M1);    // [58,60M)
    ushort_t* VTb = (ushort_t*)d_out;            // 8 MB scratch in d_out
    ushort_t* YHb = (ushort_t*)(w);              // over XH (dead after QKV)

    dim3 blk(256);
    conv_all<<<dim3(4096, 5), blk, 0, stream>>>(x, Wq, Wk, Wv, Wu,
                                                XH, XL, WqH, WqL, WkH, WkL, WvH, WuH);
    // fused Q,K,V projections: 128x128 tiles -> 32x8x3 = 768 blocks = 3/CU
    gemm_bf16<<<dim3(8, 32, 3), blk, 0, stream>>>(XH, XL, WqH, WqL, WkH, WkL, WvH, WuH,
                                                  QHb, QLb, KHb, KLb, VTb, nullptr,
                                                  nullptr, 0);
    // attention: grid(bh, qt) so each (b,h)'s 32 blocks share one XCD's L2
    attn_mfma<<<dim3(NH * 2, 32), blk, 0, stream>>>(QHb, QLb, KHb, KLb, VTb, mask, YHb);
    // output projection + bias: 128x128 tiles -> 256 blocks
    gemm_bf16<<<dim3(8, 32, 1), blk, 0, stream>>>(YHb, nullptr, WqH, WqL, WkH, WkL, WvH, WuH,
                                                  nullptr, nullptr, nullptr, nullptr, nullptr,
                                                  out, bu, 3);
}

// Round 5
// 282.975 us; speedup vs baseline: 1.8378x; 1.0489x over previous
//
#include <hip/hip_runtime.h>
#include <hip/hip_bf16.h>
#include <math.h>

#define TS 2048   // sequence length T
#define KD 1024   // model dim K
#define NH 16     // heads
#define SD 64     // head dim
#define MB 4096   // B*T rows
#define LOG2E 1.4426950408889634f

typedef __attribute__((ext_vector_type(8))) short bf16x8;   // 8 bf16 (4 VGPRs)
typedef __attribute__((ext_vector_type(4))) short bf16x4;   // 4 bf16 (2 VGPRs)
typedef __attribute__((ext_vector_type(4))) float f32x4;    // MFMA accumulator
typedef unsigned short ushort_t;

#define MFMA32(a, b, c) __builtin_amdgcn_mfma_f32_16x16x32_bf16(a, b, c, 0, 0, 0)

union frag8 { bf16x8 v8; bf16x4 h[2]; };

__device__ __forceinline__ ushort_t f2bf_rn(float f) {
    union { __hip_bfloat16 h; ushort_t u; } c;
    c.h = __float2bfloat16(f);
    return c.u;
}
__device__ __forceinline__ float bf2f(ushort_t u) {
    union { unsigned u; float f; } v; v.u = ((unsigned)u) << 16;
    return v.f;
}
__device__ __forceinline__ ushort4 pk4_bf(float a, float b, float c, float d) {
    union { __hip_bfloat162 h; ushort2 u; } x, y;
    x.h = __float22bfloat162_rn(make_float2(a, b));
    y.h = __float22bfloat162_rn(make_float2(c, d));
    return make_ushort4(x.u.x, x.u.y, y.u.x, y.u.y);
}
// hardware exp2: single v_exp_f32 (<=1 ulp; P is rounded to bf16 right after).
// exp2(-inf)=0 exactly, preserving the mask semantics. (round-4 win: -15 us)
__device__ __forceinline__ float fexp2(float x) {
#if __has_builtin(__builtin_amdgcn_exp2f)
    return __builtin_amdgcn_exp2f(x);
#else
    return exp2f(x);
#endif
}
// async global -> LDS, 16 B per lane; lds ptr must be wave-uniform
__device__ __forceinline__ void gload_lds16(const void* g, void* l) {
    __builtin_amdgcn_global_load_lds(
        (const __attribute__((address_space(1))) unsigned int*)g,
        (__attribute__((address_space(3))) unsigned int*)l, 16, 0, 0);
}

// ---------------------------------------------------------------------------
// conv_all: z=0: x -> XH,XL (hi/lo); z=1: Wq*log2e -> hi/lo (folds exp->exp2);
// z=2: Wk -> hi/lo; z=3: Wv -> hi; z=4: Wu -> hi.
// ---------------------------------------------------------------------------
__global__ __launch_bounds__(256)
void conv_all(const float* __restrict__ x, const float* __restrict__ wq,
              const float* __restrict__ wk, const float* __restrict__ wv,
              const float* __restrict__ wu,
              ushort_t* XH, ushort_t* XL, ushort_t* WqH, ushort_t* WqL,
              ushort_t* WkH, ushort_t* WkL, ushort_t* WvH, ushort_t* WuH)
{
    int z = blockIdx.y;
    const float* src; ushort_t* H; ushort_t* L = nullptr; int nblk;
    switch (z) {
        case 0:  src = x;  H = XH;  L = XL;  nblk = 4096; break;
        case 1:  src = wq; H = WqH; L = WqL; nblk = 1024; break;
        case 2:  src = wk; H = WkH; L = WkL; nblk = 1024; break;
        case 3:  src = wv; H = WvH;          nblk = 1024; break;
        default: src = wu; H = WuH;          nblk = 1024; break;
    }
    if ((int)blockIdx.x >= nblk) return;
    int idx = blockIdx.x * 256 + threadIdx.x;      // float4 index
    float4 v = ((const float4*)src)[idx];
    if (z == 1) { v.x *= LOG2E; v.y *= LOG2E; v.z *= LOG2E; v.w *= LOG2E; }
    ushort_t h0 = f2bf_rn(v.x), h1 = f2bf_rn(v.y);
    ushort_t h2 = f2bf_rn(v.z), h3 = f2bf_rn(v.w);
    ((ushort4*)H)[idx] = make_ushort4(h0, h1, h2, h3);
    if (L) {
        ushort_t l0 = f2bf_rn(v.x - bf2f(h0)), l1 = f2bf_rn(v.y - bf2f(h1));
        ushort_t l2 = f2bf_rn(v.z - bf2f(h2)), l3 = f2bf_rn(v.w - bf2f(h3));
        ((ushort4*)L)[idx] = make_ushort4(l0, l1, l2, l3);
    }
}

// ---------------------------------------------------------------------------
// MFMA GEMM: C = A @ W^T. m97 geometry: 128x128 tile, BK=32, 4 waves (2x2),
// 64x64 per wave, acc[4][4]. (unchanged — round-1 version)
// ---------------------------------------------------------------------------
__global__ __launch_bounds__(256)
void gemm_bf16(const ushort_t* __restrict__ Ah, const ushort_t* __restrict__ Al,
               const ushort_t* __restrict__ Bqh, const ushort_t* __restrict__ Bql,
               const ushort_t* __restrict__ Bkh, const ushort_t* __restrict__ Bkl,
               const ushort_t* __restrict__ Bvh, const ushort_t* __restrict__ Buh,
               ushort_t* __restrict__ OQh, ushort_t* __restrict__ OQl,
               ushort_t* __restrict__ OKh, ushort_t* __restrict__ OKl,
               ushort_t* __restrict__ OVt, float* __restrict__ OF,
               const float* __restrict__ bias, int epi_base)
{
    const int epi = epi_base + blockIdx.z;
    const ushort_t* Bh; const ushort_t* Bl = nullptr;
    if      (epi == 0) { Bh = Bqh; Bl = Bql; }
    else if (epi == 1) { Bh = Bkh; Bl = Bkl; }
    else if (epi == 2) { Bh = Bvh; }
    else               { Bh = Buh; }
    const bool terms3 = (epi < 2);

    __shared__ ushort_t sAh[128 * 32];   // 8 KB each, 32 KB total
    __shared__ ushort_t sAl[128 * 32];
    __shared__ ushort_t sBh[128 * 32];
    __shared__ ushort_t sBl[128 * 32];

    const int tid = threadIdx.x;
    const int wave = tid >> 6, lane = tid & 63;
    const int col = lane & 15, quad = lane >> 4;
    const int wm = wave >> 1, wn = wave & 1;
    const int m0 = blockIdx.y * 128, n0 = blockIdx.x * 128;

    f32x4 acc[4][4];
#pragma unroll
    for (int i = 0; i < 4; ++i)
#pragma unroll
        for (int j = 0; j < 4; ++j) acc[i][j] = (f32x4){0.f, 0.f, 0.f, 0.f};

    for (int k0 = 0; k0 < KD; k0 += 32) {
#pragma unroll
        for (int half = 0; half < 2; ++half) {
            int s   = half * 256 + wave * 64 + lane;
            int row = s >> 2, k8 = s & 3;
            int lo  = (half * 256 + wave * 64) * 8;   // wave-uniform ushort off
            gload_lds16(Ah + (size_t)(m0 + row) * KD + k0 + k8 * 8, sAh + lo);
            gload_lds16(Bh + (size_t)(n0 + row) * KD + k0 + k8 * 8, sBh + lo);
            if (terms3) {
                gload_lds16(Al + (size_t)(m0 + row) * KD + k0 + k8 * 8, sAl + lo);
                gload_lds16(Bl + (size_t)(n0 + row) * KD + k0 + k8 * 8, sBl + lo);
            }
        }
        __syncthreads();

        bf16x8 fah[4], fal[4], fbh[4], fbl[4];
#pragma unroll
        for (int j = 0; j < 4; ++j) {
            int ra = (wm * 64 + j * 16 + col) * 32 + quad * 8;
            int rb = (wn * 64 + j * 16 + col) * 32 + quad * 8;
            fah[j] = *(const bf16x8*)&sAh[ra];
            fbh[j] = *(const bf16x8*)&sBh[rb];
            if (terms3) {
                fal[j] = *(const bf16x8*)&sAl[ra];
                fbl[j] = *(const bf16x8*)&sBl[rb];
            }
        }
#pragma unroll
        for (int i = 0; i < 4; ++i) {
            if (terms3) {
#pragma unroll
                for (int j = 0; j < 4; ++j) {
                    acc[i][j] = MFMA32(fah[i], fbh[j], acc[i][j]);
                    acc[i][j] = MFMA32(fah[i], fbl[j], acc[i][j]);
                    acc[i][j] = MFMA32(fal[i], fbh[j], acc[i][j]);
                }
            } else {
#pragma unroll
                for (int j = 0; j < 4; ++j)
                    acc[i][j] = MFMA32(fah[i], fbh[j], acc[i][j]);
            }
        }
        __syncthreads();
    }

    // ---- epilogues (C/D: row m = quad*4+reg, col n = lane&15) ----
    if (epi <= 1) {
        ushort_t* OH = (epi == 0) ? OQh : OKh;
        ushort_t* OL = (epi == 0) ? OQl : OKl;
#pragma unroll
        for (int i = 0; i < 4; ++i) {
            int m = m0 + wm * 64 + i * 16 + quad * 4;
#pragma unroll
            for (int j = 0; j < 4; ++j) {
                int n = n0 + wn * 64 + j * 16 + col;
#pragma unroll
                for (int r = 0; r < 4; ++r) {
                    float v = acc[i][j][r];
                    ushort_t hv = f2bf_rn(v);
                    size_t off = (size_t)(m + r) * KD + n;
                    OH[off] = hv;
                    OL[off] = f2bf_rn(v - bf2f(hv));
                }
            }
        }
    } else if (epi == 2) {
#pragma unroll
        for (int i = 0; i < 4; ++i) {
            int m = m0 + wm * 64 + i * 16 + quad * 4;
            int bb = m >> 11, t = m & (TS - 1);
#pragma unroll
            for (int j = 0; j < 4; ++j) {
                int n = n0 + wn * 64 + j * 16 + col;
                int hh = n >> 6, d = n & 63;
                ushort4 pk = pk4_bf(acc[i][j][0], acc[i][j][1], acc[i][j][2], acc[i][j][3]);
                *(ushort4*)(OVt + ((size_t)(bb * NH + hh) * SD + d) * TS + t) = pk;
            }
        }
    } else {
#pragma unroll
        for (int i = 0; i < 4; ++i) {
            int m = m0 + wm * 64 + i * 16 + quad * 4;
#pragma unroll
            for (int j = 0; j < 4; ++j) {
                int n = n0 + wn * 64 + j * 16 + col;
                float bj = bias[n];
#pragma unroll
                for (int r = 0; r < 4; ++r)
                    OF[(size_t)(m + r) * KD + n] = acc[i][j][r] + bj;
            }
        }
    }
}

// ---------------------------------------------------------------------------
// MFMA flash attention — round-4 structure + PAIRED K-TILES: the PV MFMAs
// were zero-padded (h[1] of both operands constant 0 -> 16 of 32 k-slots
// idle). Now each loop iteration processes TWO 64-key tiles: even tile's P
// goes to bp4[].h[0], odd tile's P to bp4[].h[1]; av[] h[0]/h[1] read V^T
// from the two staged buffers. One full-K MFMA computes V0*P0 + V1*P1 ->
// PV issue halves (per pair: 32 -> 16), total MFMA issue -20%, barrier
// count halves. Same single-barrier-per-iteration staging discipline as the
// measured-best loop (dbuf prefetch was measured-worse; this is NOT a
// prefetch — both buffers are consumed in the same iteration).
// ---------------------------------------------------------------------------
__global__ __launch_bounds__(256, 2)
void attn_mfma(const ushort_t* __restrict__ QH, const ushort_t* __restrict__ QL,
               const ushort_t* __restrict__ KH, const ushort_t* __restrict__ KL,
               const ushort_t* __restrict__ VT, const int* __restrict__ mask,
               ushort_t* __restrict__ YH)
{
    const int bh = blockIdx.x;       // 0..31  (fastest dim -> pins XCD = bh%8)
    const int qt = blockIdx.y;       // 0..31
    const int h  = bh & (NH - 1);
    const int b  = bh >> 4;

    const int tid  = threadIdx.x;
    const int wave = tid >> 6;
    const int lane = tid & 63;
    const int col  = lane & 15;
    const int quad = lane >> 4;

    // 48 KB: two 24 KB tile buffers (KH 8K | KL 8K | VT 8K each), both
    // consumed per iteration; first 16 KB reused for the O-reduce.
    __shared__ ushort_t smem[24576];
    ushort_t* sKH = smem;                // [key][d] swizzled
    ushort_t* sKL = smem + 4096;
    ushort_t* sVT = smem + 8192;         // [d][key] swizzled
    const int ODD = 12288;               // ushort offset of odd-tile buffer
    __shared__ float lred[4][64];

    // ---- Q fragments, held in registers for the whole kernel ----
    bf16x8 bqh[4][2], bql[4][2];
#pragma unroll
    for (int qf = 0; qf < 4; ++qf) {
        size_t qrow = (size_t)(b * TS + qt * 64 + qf * 16 + col) * KD + h * SD;
#pragma unroll
        for (int c = 0; c < 2; ++c) {
            bqh[qf][c] = *(const bf16x8*)(QH + qrow + c * 32 + quad * 8);
            bql[qf][c] = *(const bf16x8*)(QL + qrow + c * 32 + quad * 8);
        }
    }

    // ---- hoisted staging pointers: chunk r -> {r<2: KH, r<4: KL, else VT} ----
    const int l8 = lane >> 3, l7 = lane & 7;
    const ushort_t* gp[6];
    ushort_t* ld[6];
#pragma unroll
    for (int r = 0; r < 6; ++r) {
        int cc  = (r & 1) * 4 + wave;          // chunk within its matrix (0..7)
        int row = cc * 8 + l8;                 // 0..63
        int gs  = l7 ^ (row & 7);              // XOR swizzle
        if (r < 2)      gp[r] = KH + (size_t)(b * TS + row) * KD + h * SD + gs * 8;
        else if (r < 4) gp[r] = KL + (size_t)(b * TS + row) * KD + h * SD + gs * 8;
        else            gp[r] = VT + ((size_t)bh * SD + row) * TS + gs * 8;
        ld[r] = ((r < 2) ? sKH : (r < 4) ? sKL : sVT) + cc * 512;
    }
    const int* mp = mask + b * TS + wave * 16 + quad * 4;

    float lp[4] = {0.f, 0.f, 0.f, 0.f};
    f32x4 O[4][4];                        // [dt][qf], O^T: row=d, col=q
#pragma unroll
    for (int dt = 0; dt < 4; ++dt)
#pragma unroll
        for (int qf = 0; qf < 4; ++qf) O[dt][qf] = (f32x4){0.f, 0.f, 0.f, 0.f};

    frag8 av[4], bp4[4];
#pragma unroll
    for (int i = 0; i < 4; ++i) {
        av[i].v8  = (bf16x8){0, 0, 0, 0, 0, 0, 0, 0};
        bp4[i].v8 = (bf16x8){0, 0, 0, 0, 0, 0, 0, 0};
    }

    for (int pr = 0; pr < TS / 128; ++pr) {
        // ---- stage BOTH tiles of the pair (even -> base, odd -> +ODD) ----
#pragma unroll
        for (int r = 0; r < 6; ++r) {
            gload_lds16(gp[r], ld[r]);
            gload_lds16(gp[r] + ((r < 4) ? 64 * KD : 64), ld[r] + ODD);
        }
        int4 mv0 = *(const int4*)mp;
        int4 mv1 = *(const int4*)(mp + 64);
        mp += 128;
#pragma unroll
        for (int r = 0; r < 6; ++r) gp[r] += (r < 4) ? 128 * KD : 128;
        __syncthreads();

        // ---- each half: S^T strips + exp2 -> P into bp4[].h[half] ----
#pragma unroll
        for (int half = 0; half < 2; ++half) {
            const int bo = half ? ODD : 0;
            const int4 mv = half ? mv1 : mv0;
            f32x4 sinit;
            sinit[0] = mv.x ? 0.f : -INFINITY;
            sinit[1] = mv.y ? 0.f : -INFINITY;
            sinit[2] = mv.z ? 0.f : -INFINITY;
            sinit[3] = mv.w ? 0.f : -INFINITY;

            bf16x8 akh[2], akl[2];
#pragma unroll
            for (int c = 0; c < 2; ++c) {
                int sl = (c * 4 + quad) ^ (col & 7);
                akh[c] = *(const bf16x8*)&sKH[bo + ((wave * 16 + col) * 8 + sl) * 8];
                akl[c] = *(const bf16x8*)&sKL[bo + ((wave * 16 + col) * 8 + sl) * 8];
            }
#pragma unroll
            for (int qf = 0; qf < 4; ++qf) {
                f32x4 s1 = sinit;
                f32x4 s2 = (f32x4){0.f, 0.f, 0.f, 0.f};
                s1 = MFMA32(akh[0], bqh[qf][0], s1);
                s2 = MFMA32(akl[0], bqh[qf][0], s2);
                s2 = MFMA32(akh[0], bql[qf][0], s2);
                s1 = MFMA32(akh[1], bqh[qf][1], s1);
                s2 = MFMA32(akl[1], bqh[qf][1], s2);
                s2 = MFMA32(akh[1], bql[qf][1], s2);
                float p0 = fexp2(s1[0] + s2[0]);
                float p1 = fexp2(s1[1] + s2[1]);
                float p2 = fexp2(s1[2] + s2[2]);
                float p3 = fexp2(s1[3] + s2[3]);
                lp[qf] += (p0 + p1) + (p2 + p3);
                union { ushort4 u4; bf16x4 v4; } pk;
                pk.u4 = pk4_bf(p0, p1, p2, p3);
                bp4[qf].h[half] = pk.v4;
            }
        }

        // ---- V^T fragments: h[0] even tile, h[1] odd tile ----
#pragma unroll
        for (int dt = 0; dt < 4; ++dt) {
            int sl = (wave * 2 + (quad >> 1)) ^ (col & 7);
            int so = ((dt * 16 + col) * 8 + sl) * 8 + (quad & 1) * 4;
            av[dt].h[0] = *(const bf16x4*)&sVT[so];
            av[dt].h[1] = *(const bf16x4*)&sVT[ODD + so];
        }

        // ---- O^T += V^T x P^T, full-K MFMA (V0*P0 + V1*P1 fused) ----
#pragma unroll
        for (int dt = 0; dt < 4; ++dt)
#pragma unroll
            for (int qf = 0; qf < 4; ++qf)
                O[dt][qf] = MFMA32(av[dt].v8, bp4[qf].v8, O[dt][qf]);

        __syncthreads();
    }

    // ---- l: reduce over quads, publish per wave ----
#pragma unroll
    for (int qf = 0; qf < 4; ++qf) {
        float v = lp[qf];
        v += __shfl_xor(v, 16);
        v += __shfl_xor(v, 32);
        if (lane < 16) lred[wave][qf * 16 + lane] = v;
    }

    // ---- staged O-reduce through 16 KB of LDS (3 rounds) ----
    float* Of = (float*)smem;
#pragma unroll
    for (int w = 1; w < 4; ++w) {
        __syncthreads();
        if (wave == w) {
#pragma unroll
            for (int dt = 0; dt < 4; ++dt)
#pragma unroll
                for (int qf = 0; qf < 4; ++qf)
                    *(f32x4*)&Of[((dt * 4 + qf) * 64 + lane) * 4] = O[dt][qf];
        }
        __syncthreads();
        if (wave == 0) {
#pragma unroll
            for (int dt = 0; dt < 4; ++dt)
#pragma unroll
                for (int qf = 0; qf < 4; ++qf)
                    O[dt][qf] += *(const f32x4*)&Of[((dt * 4 + qf) * 64 + lane) * 4];
        }
    }
    if (wave == 0) {
        float linv[4];
#pragma unroll
        for (int qf = 0; qf < 4; ++qf) {
            int q = qf * 16 + col;
            linv[qf] = 1.f / (lred[0][q] + lred[1][q] + lred[2][q] + lred[3][q]);
        }
#pragma unroll
        for (int dt = 0; dt < 4; ++dt)
#pragma unroll
            for (int qf = 0; qf < 4; ++qf) {
                ushort4 pk = pk4_bf(O[dt][qf][0] * linv[qf], O[dt][qf][1] * linv[qf],
                                    O[dt][qf][2] * linv[qf], O[dt][qf][3] * linv[qf]);
                *(ushort4*)(YH + (size_t)(b * TS + qt * 64 + qf * 16 + col) * KD +
                            h * SD + dt * 16 + quad * 4) = pk;
            }
    }
}

// ---------------------------------------------------------------------------
extern "C" void kernel_launch(void* const* d_in, const int* in_sizes, int n_in,
                              void* d_out, int out_size, void* d_ws, size_t ws_size,
                              hipStream_t stream) {
    const float* x    = (const float*)d_in[0];
    const int*   mask = (const int*)d_in[1];
    const float* Wk   = (const float*)d_in[2];
    const float* Wq   = (const float*)d_in[3];
    const float* Wv   = (const float*)d_in[4];
    const float* Wu   = (const float*)d_in[5];
    const float* bu   = (const float*)d_in[6];
    float* out = (float*)d_out;

    char* w = (char*)d_ws;
    const size_t M1 = (size_t)1 << 20;
    // workspace plan (60 MB peak; VT lives in d_out until the U gemm):
    ushort_t* XH  = (ushort_t*)(w);              // [0,8M)
    ushort_t* XL  = (ushort_t*)(w + 8  * M1);    // [8,16M)
    ushort_t* WqH = (ushort_t*)(w + 16 * M1);
    ushort_t* WqL = (ushort_t*)(w + 18 * M1);
    ushort_t* WkH = (ushort_t*)(w + 20 * M1);
    ushort_t* WkL = (ushort_t*)(w + 22 * M1);
    ushort_t* WvH = (ushort_t*)(w + 24 * M1);    // [24,26M)
    ushort_t* QHb = (ushort_t*)(w + 26 * M1);    // [26,34M)
    ushort_t* QLb = (ushort_t*)(w + 34 * M1);
    ushort_t* KHb = (ushort_t*)(w + 42 * M1);
    ushort_t* KLb = (ushort_t*)(w + 50 * M1);    // ..58M
    ushort_t* WuH = (ushort_t*)(w + 58 * M1);    // [58,60M)
    ushort_t* VTb = (ushort_t*)d_out;            // 8 MB scratch in d_out
    ushort_t* YHb = (ushort_t*)(w);              // over XH (dead after QKV)

    dim3 blk(256);
    conv_all<<<dim3(4096, 5), blk, 0, stream>>>(x, Wq, Wk, Wv, Wu,
                                                XH, XL, WqH, WqL, WkH, WkL, WvH, WuH);
    // fused Q,K,V projections: 128x128 tiles -> 32x8x3 = 768 blocks = 3/CU
    gemm_bf16<<<dim3(8, 32, 3), blk, 0, stream>>>(XH, XL, WqH, WqL, WkH, WkL, WvH, WuH,
                                                  QHb, QLb, KHb, KLb, VTb, nullptr,
                                                  nullptr, 0);
    // attention: grid(bh, qt) so each (b,h)'s 32 blocks share one XCD's L2
    attn_mfma<<<dim3(NH * 2, 32), blk, 0, stream>>>(QHb, QLb, KHb, KLb, VTb, mask, YHb);
    // output projection + bias: 128x128 tiles -> 256 blocks
    gemm_bf16<<<dim3(8, 32, 1), blk, 0, stream>>>(YHb, nullptr, WqH, WqL, WkH, WkL, WvH, WuH,
                                                  nullptr, nullptr, nullptr, nullptr, nullptr,
                                                  out, bu, 3);
}

// Round 6
// 259.365 us; speedup vs baseline: 2.0051x; 1.0910x over previous
//
#include <hip/hip_runtime.h>
#include <hip/hip_bf16.h>
#include <math.h>

#define TS 2048   // sequence length T
#define KD 1024   // model dim K
#define NH 16     // heads
#define SD 64     // head dim
#define MB 4096   // B*T rows
#define LOG2E 1.4426950408889634f

typedef __attribute__((ext_vector_type(8))) short bf16x8;   // 8 bf16 (4 VGPRs)
typedef __attribute__((ext_vector_type(4))) short bf16x4;   // 4 bf16 (2 VGPRs)
typedef __attribute__((ext_vector_type(4))) float f32x4;    // MFMA accumulator
typedef unsigned short ushort_t;

#define MFMA32(a, b, c) __builtin_amdgcn_mfma_f32_16x16x32_bf16(a, b, c, 0, 0, 0)

union frag8 { bf16x8 v8; bf16x4 h[2]; };

__device__ __forceinline__ ushort_t f2bf_rn(float f) {
    union { __hip_bfloat16 h; ushort_t u; } c;
    c.h = __float2bfloat16(f);
    return c.u;
}
__device__ __forceinline__ float bf2f(ushort_t u) {
    union { unsigned u; float f; } v; v.u = ((unsigned)u) << 16;
    return v.f;
}
__device__ __forceinline__ ushort4 pk4_bf(float a, float b, float c, float d) {
    union { __hip_bfloat162 h; ushort2 u; } x, y;
    x.h = __float22bfloat162_rn(make_float2(a, b));
    y.h = __float22bfloat162_rn(make_float2(c, d));
    return make_ushort4(x.u.x, x.u.y, y.u.x, y.u.y);
}
// hardware exp2: single v_exp_f32 (<=1 ulp; P is rounded to bf16 right after).
// exp2(-inf)=0 exactly, preserving the mask semantics. (round-4 win: -15 us)
__device__ __forceinline__ float fexp2(float x) {
#if __has_builtin(__builtin_amdgcn_exp2f)
    return __builtin_amdgcn_exp2f(x);
#else
    return exp2f(x);
#endif
}
// async global -> LDS, 16 B per lane; lds ptr must be wave-uniform
__device__ __forceinline__ void gload_lds16(const void* g, void* l) {
    __builtin_amdgcn_global_load_lds(
        (const __attribute__((address_space(1))) unsigned int*)g,
        (__attribute__((address_space(3))) unsigned int*)l, 16, 0, 0);
}

// ---------------------------------------------------------------------------
// conv_all: z=0: x -> XH,XL (hi/lo); z=1: Wq*log2e -> hi/lo (folds exp->exp2);
// z=2: Wk -> hi/lo; z=3: Wv -> hi; z=4: Wu -> hi.
// ---------------------------------------------------------------------------
__global__ __launch_bounds__(256)
void conv_all(const float* __restrict__ x, const float* __restrict__ wq,
              const float* __restrict__ wk, const float* __restrict__ wv,
              const float* __restrict__ wu,
              ushort_t* XH, ushort_t* XL, ushort_t* WqH, ushort_t* WqL,
              ushort_t* WkH, ushort_t* WkL, ushort_t* WvH, ushort_t* WuH)
{
    int z = blockIdx.y;
    const float* src; ushort_t* H; ushort_t* L = nullptr; int nblk;
    switch (z) {
        case 0:  src = x;  H = XH;  L = XL;  nblk = 4096; break;
        case 1:  src = wq; H = WqH; L = WqL; nblk = 1024; break;
        case 2:  src = wk; H = WkH; L = WkL; nblk = 1024; break;
        case 3:  src = wv; H = WvH;          nblk = 1024; break;
        default: src = wu; H = WuH;          nblk = 1024; break;
    }
    if ((int)blockIdx.x >= nblk) return;
    int idx = blockIdx.x * 256 + threadIdx.x;      // float4 index
    float4 v = ((const float4*)src)[idx];
    if (z == 1) { v.x *= LOG2E; v.y *= LOG2E; v.z *= LOG2E; v.w *= LOG2E; }
    ushort_t h0 = f2bf_rn(v.x), h1 = f2bf_rn(v.y);
    ushort_t h2 = f2bf_rn(v.z), h3 = f2bf_rn(v.w);
    ((ushort4*)H)[idx] = make_ushort4(h0, h1, h2, h3);
    if (L) {
        ushort_t l0 = f2bf_rn(v.x - bf2f(h0)), l1 = f2bf_rn(v.y - bf2f(h1));
        ushort_t l2 = f2bf_rn(v.z - bf2f(h2)), l3 = f2bf_rn(v.w - bf2f(h3));
        ((ushort4*)L)[idx] = make_ushort4(l0, l1, l2, l3);
    }
}

// ---------------------------------------------------------------------------
// MFMA GEMM: C = A @ W^T. 128x128 tile, 4 waves (2x2), 64x64/wave, acc[4][4].
// Round-6 changes (counter-driven: QKV dispatch showed 5.24M LDS bank
// conflicts + everything-low latency-bound profile):
//  * BK 32 -> 64: halves barrier count; the 2-phase stage+vmcnt+barrier
//    overhead amortizes over 2x compute per step. LDS 64 KB, still 2
//    blocks/CU (VGPR-bound at 2 anyway).
//  * LDS XOR swizzle, both-sides involution: at BK=64 the row stride is
//    128 B (32-way conflict pattern). LDS dest stays LINEAR (required by
//    global_load_lds); the GLOBAL source k-block is pre-swizzled
//    kb = j ^ (row&7); the ds_read applies the same XOR. Each aligned
//    8-lane read group then covers all 32 banks exactly once.
//  MFMA k-order and 3-term sequence unchanged -> bit-identical output.
// ---------------------------------------------------------------------------
__global__ __launch_bounds__(256)
void gemm_bf16(const ushort_t* __restrict__ Ah, const ushort_t* __restrict__ Al,
               const ushort_t* __restrict__ Bqh, const ushort_t* __restrict__ Bql,
               const ushort_t* __restrict__ Bkh, const ushort_t* __restrict__ Bkl,
               const ushort_t* __restrict__ Bvh, const ushort_t* __restrict__ Buh,
               ushort_t* __restrict__ OQh, ushort_t* __restrict__ OQl,
               ushort_t* __restrict__ OKh, ushort_t* __restrict__ OKl,
               ushort_t* __restrict__ OVt, float* __restrict__ OF,
               const float* __restrict__ bias, int epi_base)
{
    const int epi = epi_base + blockIdx.z;
    const ushort_t* Bh; const ushort_t* Bl = nullptr;
    if      (epi == 0) { Bh = Bqh; Bl = Bql; }
    else if (epi == 1) { Bh = Bkh; Bl = Bkl; }
    else if (epi == 2) { Bh = Bvh; }
    else               { Bh = Buh; }
    const bool terms3 = (epi < 2);

    __shared__ ushort_t sAh[128 * 64];   // 16 KB each, 64 KB total
    __shared__ ushort_t sAl[128 * 64];
    __shared__ ushort_t sBh[128 * 64];
    __shared__ ushort_t sBl[128 * 64];

    const int tid = threadIdx.x;
    const int wave = tid >> 6, lane = tid & 63;
    const int col = lane & 15, quad = lane >> 4;
    const int wm = wave >> 1, wn = wave & 1;
    const int m0 = blockIdx.y * 128, n0 = blockIdx.x * 128;

    f32x4 acc[4][4];
#pragma unroll
    for (int i = 0; i < 4; ++i)
#pragma unroll
        for (int j = 0; j < 4; ++j) acc[i][j] = (f32x4){0.f, 0.f, 0.f, 0.f};

    for (int k0 = 0; k0 < KD; k0 += 64) {
        // stage: 128 rows x 8 16B-slots per matrix = 1024 slots, 4/thread.
        // LDS linear in slot order; global k-block XOR-swizzled by row.
#pragma unroll
        for (int p = 0; p < 4; ++p) {
            int s   = p * 256 + wave * 64 + lane;
            int row = s >> 3, j = s & 7;
            int kb  = j ^ (row & 7);                  // swizzle involution
            int lo  = (p * 256 + wave * 64) * 8;      // wave-uniform ushort off
            size_t ga = (size_t)(m0 + row) * KD + k0 + kb * 8;
            size_t gb = (size_t)(n0 + row) * KD + k0 + kb * 8;
            gload_lds16(Ah + ga, sAh + lo);
            gload_lds16(Bh + gb, sBh + lo);
            if (terms3) {
                gload_lds16(Al + ga, sAl + lo);
                gload_lds16(Bl + gb, sBl + lo);
            }
        }
        __syncthreads();

#pragma unroll
        for (int kk = 0; kk < 2; ++kk) {
            bf16x8 fah[4], fal[4], fbh[4], fbl[4];
            const int sw = (kk * 4 + quad) ^ (col & 7);   // swizzled 16B slot
#pragma unroll
            for (int j = 0; j < 4; ++j) {
                int ra = (wm * 64 + j * 16 + col) * 64 + sw * 8;
                int rb = (wn * 64 + j * 16 + col) * 64 + sw * 8;
                fah[j] = *(const bf16x8*)&sAh[ra];
                fbh[j] = *(const bf16x8*)&sBh[rb];
                if (terms3) {
                    fal[j] = *(const bf16x8*)&sAl[ra];
                    fbl[j] = *(const bf16x8*)&sBl[rb];
                }
            }
#pragma unroll
            for (int i = 0; i < 4; ++i) {
                if (terms3) {
#pragma unroll
                    for (int j = 0; j < 4; ++j) {
                        acc[i][j] = MFMA32(fah[i], fbh[j], acc[i][j]);
                        acc[i][j] = MFMA32(fah[i], fbl[j], acc[i][j]);
                        acc[i][j] = MFMA32(fal[i], fbh[j], acc[i][j]);
                    }
                } else {
#pragma unroll
                    for (int j = 0; j < 4; ++j)
                        acc[i][j] = MFMA32(fah[i], fbh[j], acc[i][j]);
                }
            }
        }
        __syncthreads();
    }

    // ---- epilogues (C/D: row m = quad*4+reg, col n = lane&15) ----
    if (epi <= 1) {
        ushort_t* OH = (epi == 0) ? OQh : OKh;
        ushort_t* OL = (epi == 0) ? OQl : OKl;
#pragma unroll
        for (int i = 0; i < 4; ++i) {
            int m = m0 + wm * 64 + i * 16 + quad * 4;
#pragma unroll
            for (int j = 0; j < 4; ++j) {
                int n = n0 + wn * 64 + j * 16 + col;
#pragma unroll
                for (int r = 0; r < 4; ++r) {
                    float v = acc[i][j][r];
                    ushort_t hv = f2bf_rn(v);
                    size_t off = (size_t)(m + r) * KD + n;
                    OH[off] = hv;
                    OL[off] = f2bf_rn(v - bf2f(hv));
                }
            }
        }
    } else if (epi == 2) {
#pragma unroll
        for (int i = 0; i < 4; ++i) {
            int m = m0 + wm * 64 + i * 16 + quad * 4;
            int bb = m >> 11, t = m & (TS - 1);
#pragma unroll
            for (int j = 0; j < 4; ++j) {
                int n = n0 + wn * 64 + j * 16 + col;
                int hh = n >> 6, d = n & 63;
                ushort4 pk = pk4_bf(acc[i][j][0], acc[i][j][1], acc[i][j][2], acc[i][j][3]);
                *(ushort4*)(OVt + ((size_t)(bb * NH + hh) * SD + d) * TS + t) = pk;
            }
        }
    } else {
#pragma unroll
        for (int i = 0; i < 4; ++i) {
            int m = m0 + wm * 64 + i * 16 + quad * 4;
#pragma unroll
            for (int j = 0; j < 4; ++j) {
                int n = n0 + wn * 64 + j * 16 + col;
                float bj = bias[n];
#pragma unroll
                for (int r = 0; r < 4; ++r)
                    OF[(size_t)(m + r) * KD + n] = acc[i][j][r] + bj;
            }
        }
    }
}

// ---------------------------------------------------------------------------
// MFMA flash attention — round-5 version (paired K-tiles, full-K PV MFMAs;
// measured win). Unchanged this round.
// ---------------------------------------------------------------------------
__global__ __launch_bounds__(256, 2)
void attn_mfma(const ushort_t* __restrict__ QH, const ushort_t* __restrict__ QL,
               const ushort_t* __restrict__ KH, const ushort_t* __restrict__ KL,
               const ushort_t* __restrict__ VT, const int* __restrict__ mask,
               ushort_t* __restrict__ YH)
{
    const int bh = blockIdx.x;       // 0..31  (fastest dim -> pins XCD = bh%8)
    const int qt = blockIdx.y;       // 0..31
    const int h  = bh & (NH - 1);
    const int b  = bh >> 4;

    const int tid  = threadIdx.x;
    const int wave = tid >> 6;
    const int lane = tid & 63;
    const int col  = lane & 15;
    const int quad = lane >> 4;

    // 48 KB: two 24 KB tile buffers (KH 8K | KL 8K | VT 8K each), both
    // consumed per iteration; first 16 KB reused for the O-reduce.
    __shared__ ushort_t smem[24576];
    ushort_t* sKH = smem;                // [key][d] swizzled
    ushort_t* sKL = smem + 4096;
    ushort_t* sVT = smem + 8192;         // [d][key] swizzled
    const int ODD = 12288;               // ushort offset of odd-tile buffer
    __shared__ float lred[4][64];

    // ---- Q fragments, held in registers for the whole kernel ----
    bf16x8 bqh[4][2], bql[4][2];
#pragma unroll
    for (int qf = 0; qf < 4; ++qf) {
        size_t qrow = (size_t)(b * TS + qt * 64 + qf * 16 + col) * KD + h * SD;
#pragma unroll
        for (int c = 0; c < 2; ++c) {
            bqh[qf][c] = *(const bf16x8*)(QH + qrow + c * 32 + quad * 8);
            bql[qf][c] = *(const bf16x8*)(QL + qrow + c * 32 + quad * 8);
        }
    }

    // ---- hoisted staging pointers: chunk r -> {r<2: KH, r<4: KL, else VT} ----
    const int l8 = lane >> 3, l7 = lane & 7;
    const ushort_t* gp[6];
    ushort_t* ld[6];
#pragma unroll
    for (int r = 0; r < 6; ++r) {
        int cc  = (r & 1) * 4 + wave;          // chunk within its matrix (0..7)
        int row = cc * 8 + l8;                 // 0..63
        int gs  = l7 ^ (row & 7);              // XOR swizzle
        if (r < 2)      gp[r] = KH + (size_t)(b * TS + row) * KD + h * SD + gs * 8;
        else if (r < 4) gp[r] = KL + (size_t)(b * TS + row) * KD + h * SD + gs * 8;
        else            gp[r] = VT + ((size_t)bh * SD + row) * TS + gs * 8;
        ld[r] = ((r < 2) ? sKH : (r < 4) ? sKL : sVT) + cc * 512;
    }
    const int* mp = mask + b * TS + wave * 16 + quad * 4;

    float lp[4] = {0.f, 0.f, 0.f, 0.f};
    f32x4 O[4][4];                        // [dt][qf], O^T: row=d, col=q
#pragma unroll
    for (int dt = 0; dt < 4; ++dt)
#pragma unroll
        for (int qf = 0; qf < 4; ++qf) O[dt][qf] = (f32x4){0.f, 0.f, 0.f, 0.f};

    frag8 av[4], bp4[4];
#pragma unroll
    for (int i = 0; i < 4; ++i) {
        av[i].v8  = (bf16x8){0, 0, 0, 0, 0, 0, 0, 0};
        bp4[i].v8 = (bf16x8){0, 0, 0, 0, 0, 0, 0, 0};
    }

    for (int pr = 0; pr < TS / 128; ++pr) {
        // ---- stage BOTH tiles of the pair (even -> base, odd -> +ODD) ----
#pragma unroll
        for (int r = 0; r < 6; ++r) {
            gload_lds16(gp[r], ld[r]);
            gload_lds16(gp[r] + ((r < 4) ? 64 * KD : 64), ld[r] + ODD);
        }
        int4 mv0 = *(const int4*)mp;
        int4 mv1 = *(const int4*)(mp + 64);
        mp += 128;
#pragma unroll
        for (int r = 0; r < 6; ++r) gp[r] += (r < 4) ? 128 * KD : 128;
        __syncthreads();

        // ---- each half: S^T strips + exp2 -> P into bp4[].h[half] ----
#pragma unroll
        for (int half = 0; half < 2; ++half) {
            const int bo = half ? ODD : 0;
            const int4 mv = half ? mv1 : mv0;
            f32x4 sinit;
            sinit[0] = mv.x ? 0.f : -INFINITY;
            sinit[1] = mv.y ? 0.f : -INFINITY;
            sinit[2] = mv.z ? 0.f : -INFINITY;
            sinit[3] = mv.w ? 0.f : -INFINITY;

            bf16x8 akh[2], akl[2];
#pragma unroll
            for (int c = 0; c < 2; ++c) {
                int sl = (c * 4 + quad) ^ (col & 7);
                akh[c] = *(const bf16x8*)&sKH[bo + ((wave * 16 + col) * 8 + sl) * 8];
                akl[c] = *(const bf16x8*)&sKL[bo + ((wave * 16 + col) * 8 + sl) * 8];
            }
#pragma unroll
            for (int qf = 0; qf < 4; ++qf) {
                f32x4 s1 = sinit;
                f32x4 s2 = (f32x4){0.f, 0.f, 0.f, 0.f};
                s1 = MFMA32(akh[0], bqh[qf][0], s1);
                s2 = MFMA32(akl[0], bqh[qf][0], s2);
                s2 = MFMA32(akh[0], bql[qf][0], s2);
                s1 = MFMA32(akh[1], bqh[qf][1], s1);
                s2 = MFMA32(akl[1], bqh[qf][1], s2);
                s2 = MFMA32(akh[1], bql[qf][1], s2);
                float p0 = fexp2(s1[0] + s2[0]);
                float p1 = fexp2(s1[1] + s2[1]);
                float p2 = fexp2(s1[2] + s2[2]);
                float p3 = fexp2(s1[3] + s2[3]);
                lp[qf] += (p0 + p1) + (p2 + p3);
                union { ushort4 u4; bf16x4 v4; } pk;
                pk.u4 = pk4_bf(p0, p1, p2, p3);
                bp4[qf].h[half] = pk.v4;
            }
        }

        // ---- V^T fragments: h[0] even tile, h[1] odd tile ----
#pragma unroll
        for (int dt = 0; dt < 4; ++dt) {
            int sl = (wave * 2 + (quad >> 1)) ^ (col & 7);
            int so = ((dt * 16 + col) * 8 + sl) * 8 + (quad & 1) * 4;
            av[dt].h[0] = *(const bf16x4*)&sVT[so];
            av[dt].h[1] = *(const bf16x4*)&sVT[ODD + so];
        }

        // ---- O^T += V^T x P^T, full-K MFMA (V0*P0 + V1*P1 fused) ----
#pragma unroll
        for (int dt = 0; dt < 4; ++dt)
#pragma unroll
            for (int qf = 0; qf < 4; ++qf)
                O[dt][qf] = MFMA32(av[dt].v8, bp4[qf].v8, O[dt][qf]);

        __syncthreads();
    }

    // ---- l: reduce over quads, publish per wave ----
#pragma unroll
    for (int qf = 0; qf < 4; ++qf) {
        float v = lp[qf];
        v += __shfl_xor(v, 16);
        v += __shfl_xor(v, 32);
        if (lane < 16) lred[wave][qf * 16 + lane] = v;
    }

    // ---- staged O-reduce through 16 KB of LDS (3 rounds) ----
    float* Of = (float*)smem;
#pragma unroll
    for (int w = 1; w < 4; ++w) {
        __syncthreads();
        if (wave == w) {
#pragma unroll
            for (int dt = 0; dt < 4; ++dt)
#pragma unroll
                for (int qf = 0; qf < 4; ++qf)
                    *(f32x4*)&Of[((dt * 4 + qf) * 64 + lane) * 4] = O[dt][qf];
        }
        __syncthreads();
        if (wave == 0) {
#pragma unroll
            for (int dt = 0; dt < 4; ++dt)
#pragma unroll
                for (int qf = 0; qf < 4; ++qf)
                    O[dt][qf] += *(const f32x4*)&Of[((dt * 4 + qf) * 64 + lane) * 4];
        }
    }
    if (wave == 0) {
        float linv[4];
#pragma unroll
        for (int qf = 0; qf < 4; ++qf) {
            int q = qf * 16 + col;
            linv[qf] = 1.f / (lred[0][q] + lred[1][q] + lred[2][q] + lred[3][q]);
        }
#pragma unroll
        for (int dt = 0; dt < 4; ++dt)
#pragma unroll
            for (int qf = 0; qf < 4; ++qf) {
                ushort4 pk = pk4_bf(O[dt][qf][0] * linv[qf], O[dt][qf][1] * linv[qf],
                                    O[dt][qf][2] * linv[qf], O[dt][qf][3] * linv[qf]);
                *(ushort4*)(YH + (size_t)(b * TS + qt * 64 + qf * 16 + col) * KD +
                            h * SD + dt * 16 + quad * 4) = pk;
            }
    }
}

// ---------------------------------------------------------------------------
extern "C" void kernel_launch(void* const* d_in, const int* in_sizes, int n_in,
                              void* d_out, int out_size, void* d_ws, size_t ws_size,
                              hipStream_t stream) {
    const float* x    = (const float*)d_in[0];
    const int*   mask = (const int*)d_in[1];
    const float* Wk   = (const float*)d_in[2];
    const float* Wq   = (const float*)d_in[3];
    const float* Wv   = (const float*)d_in[4];
    const float* Wu   = (const float*)d_in[5];
    const float* bu   = (const float*)d_in[6];
    float* out = (float*)d_out;

    char* w = (char*)d_ws;
    const size_t M1 = (size_t)1 << 20;
    // workspace plan (60 MB peak; VT lives in d_out until the U gemm):
    ushort_t* XH  = (ushort_t*)(w);              // [0,8M)
    ushort_t* XL  = (ushort_t*)(w + 8  * M1);    // [8,16M)
    ushort_t* WqH = (ushort_t*)(w + 16 * M1);
    ushort_t* WqL = (ushort_t*)(w + 18 * M1);
    ushort_t* WkH = (ushort_t*)(w + 20 * M1);
    ushort_t* WkL = (ushort_t*)(w + 22 * M1);
    ushort_t* WvH = (ushort_t*)(w + 24 * M1);    // [24,26M)
    ushort_t* QHb = (ushort_t*)(w + 26 * M1);    // [26,34M)
    ushort_t* QLb = (ushort_t*)(w + 34 * M1);
    ushort_t* KHb = (ushort_t*)(w + 42 * M1);
    ushort_t* KLb = (ushort_t*)(w + 50 * M1);    // ..58M
    ushort_t* WuH = (ushort_t*)(w + 58 * M1);    // [58,60M)
    ushort_t* VTb = (ushort_t*)d_out;            // 8 MB scratch in d_out
    ushort_t* YHb = (ushort_t*)(w);              // over XH (dead after QKV)

    dim3 blk(256);
    conv_all<<<dim3(4096, 5), blk, 0, stream>>>(x, Wq, Wk, Wv, Wu,
                                                XH, XL, WqH, WqL, WkH, WkL, WvH, WuH);
    // fused Q,K,V projections: 128x128 tiles -> 32x8x3 = 768 blocks
    gemm_bf16<<<dim3(8, 32, 3), blk, 0, stream>>>(XH, XL, WqH, WqL, WkH, WkL, WvH, WuH,
                                                  QHb, QLb, KHb, KLb, VTb, nullptr,
                                                  nullptr, 0);
    // attention: grid(bh, qt) so each (b,h)'s 32 blocks share one XCD's L2
    attn_mfma<<<dim3(NH * 2, 32), blk, 0, stream>>>(QHb, QLb, KHb, KLb, VTb, mask, YHb);
    // output projection + bias: 128x128 tiles -> 256 blocks
    gemm_bf16<<<dim3(8, 32, 1), blk, 0, stream>>>(YHb, nullptr, WqH, WqL, WkH, WkL, WvH, WuH,
                                                  nullptr, nullptr, nullptr, nullptr, nullptr,
                                                  out, bu, 3);
}

// Round 7
// 255.052 us; speedup vs baseline: 2.0390x; 1.0169x over previous
//
#include <hip/hip_runtime.h>
#include <hip/hip_bf16.h>
#include <math.h>

#define TS 2048   // sequence length T
#define KD 1024   // model dim K
#define NH 16     // heads
#define SD 64     // head dim
#define MB 4096   // B*T rows
#define LOG2E 1.4426950408889634f

typedef __attribute__((ext_vector_type(8))) short bf16x8;   // 8 bf16 (4 VGPRs)
typedef __attribute__((ext_vector_type(4))) short bf16x4;   // 4 bf16 (2 VGPRs)
typedef __attribute__((ext_vector_type(4))) float f32x4;    // MFMA accumulator
typedef unsigned short ushort_t;

#define MFMA32(a, b, c) __builtin_amdgcn_mfma_f32_16x16x32_bf16(a, b, c, 0, 0, 0)

union frag8 { bf16x8 v8; bf16x4 h[2]; };

__device__ __forceinline__ ushort_t f2bf_rn(float f) {
    union { __hip_bfloat16 h; ushort_t u; } c;
    c.h = __float2bfloat16(f);
    return c.u;
}
__device__ __forceinline__ float bf2f(ushort_t u) {
    union { unsigned u; float f; } v; v.u = ((unsigned)u) << 16;
    return v.f;
}
__device__ __forceinline__ ushort4 pk4_bf(float a, float b, float c, float d) {
    union { __hip_bfloat162 h; ushort2 u; } x, y;
    x.h = __float22bfloat162_rn(make_float2(a, b));
    y.h = __float22bfloat162_rn(make_float2(c, d));
    return make_ushort4(x.u.x, x.u.y, y.u.x, y.u.y);
}
// hardware exp2: single v_exp_f32 (<=1 ulp; P is rounded to bf16 right after).
// exp2(-inf)=0 exactly, preserving the mask semantics. (round-4 win: -15 us)
__device__ __forceinline__ float fexp2(float x) {
#if __has_builtin(__builtin_amdgcn_exp2f)
    return __builtin_amdgcn_exp2f(x);
#else
    return exp2f(x);
#endif
}
// async global -> LDS, 16 B per lane; lds ptr must be wave-uniform
__device__ __forceinline__ void gload_lds16(const void* g, void* l) {
    __builtin_amdgcn_global_load_lds(
        (const __attribute__((address_space(1))) unsigned int*)g,
        (__attribute__((address_space(3))) unsigned int*)l, 16, 0, 0);
}

// ---------------------------------------------------------------------------
// conv_all — compacted grid (1024 x 8), every block does work:
//   z=0..3: x slice z -> XH,XL (hi/lo)
//   z=4: Wq*log2e -> hi/lo (folds exp->exp2); z=5: Wk -> hi/lo;
//   z=6: Wv -> hi; z=7: Wu -> hi.
// ---------------------------------------------------------------------------
__global__ __launch_bounds__(256)
void conv_all(const float* __restrict__ x, const float* __restrict__ wq,
              const float* __restrict__ wk, const float* __restrict__ wv,
              const float* __restrict__ wu,
              ushort_t* XH, ushort_t* XL, ushort_t* WqH, ushort_t* WqL,
              ushort_t* WkH, ushort_t* WkL, ushort_t* WvH, ushort_t* WuH)
{
    int z = blockIdx.y;
    const float* src; ushort_t* H; ushort_t* L = nullptr;
    int idx;
    bool scale = false;
    if (z < 4) {
        src = x; H = XH; L = XL;
        idx = (z * 1024 + blockIdx.x) * 256 + threadIdx.x;
    } else {
        idx = blockIdx.x * 256 + threadIdx.x;
        switch (z) {
            case 4:  src = wq; H = WqH; L = WqL; scale = true; break;
            case 5:  src = wk; H = WkH; L = WkL; break;
            case 6:  src = wv; H = WvH;          break;
            default: src = wu; H = WuH;          break;
        }
    }
    float4 v = ((const float4*)src)[idx];
    if (scale) { v.x *= LOG2E; v.y *= LOG2E; v.z *= LOG2E; v.w *= LOG2E; }
    ushort_t h0 = f2bf_rn(v.x), h1 = f2bf_rn(v.y);
    ushort_t h2 = f2bf_rn(v.z), h3 = f2bf_rn(v.w);
    ((ushort4*)H)[idx] = make_ushort4(h0, h1, h2, h3);
    if (L) {
        ushort_t l0 = f2bf_rn(v.x - bf2f(h0)), l1 = f2bf_rn(v.y - bf2f(h1));
        ushort_t l2 = f2bf_rn(v.z - bf2f(h2)), l3 = f2bf_rn(v.w - bf2f(h3));
        ((ushort4*)L)[idx] = make_ushort4(l0, l1, l2, l3);
    }
}

// ---------------------------------------------------------------------------
// MFMA GEMM: C = A @ W^T. 128x128 tile, 4 waves (2x2), 64x64/wave, acc[4][4].
// BK=64 + both-sides XOR swizzle (round-6 win: QKV 107.5 -> <91 us; bank
// conflicts were 5.24M). LDS dest linear (global_load_lds requirement);
// global source k-block pre-swizzled kb = j ^ (row&7); ds_read applies the
// same involution. MFMA k-order / 3-term sequence bit-identical.
// ---------------------------------------------------------------------------
__global__ __launch_bounds__(256)
void gemm_bf16(const ushort_t* __restrict__ Ah, const ushort_t* __restrict__ Al,
               const ushort_t* __restrict__ Bqh, const ushort_t* __restrict__ Bql,
               const ushort_t* __restrict__ Bkh, const ushort_t* __restrict__ Bkl,
               const ushort_t* __restrict__ Bvh, const ushort_t* __restrict__ Buh,
               ushort_t* __restrict__ OQh, ushort_t* __restrict__ OQl,
               ushort_t* __restrict__ OKh, ushort_t* __restrict__ OKl,
               ushort_t* __restrict__ OVt, float* __restrict__ OF,
               const float* __restrict__ bias, int epi_base)
{
    const int epi = epi_base + blockIdx.z;
    const ushort_t* Bh; const ushort_t* Bl = nullptr;
    if      (epi == 0) { Bh = Bqh; Bl = Bql; }
    else if (epi == 1) { Bh = Bkh; Bl = Bkl; }
    else if (epi == 2) { Bh = Bvh; }
    else               { Bh = Buh; }
    const bool terms3 = (epi < 2);

    __shared__ ushort_t sAh[128 * 64];   // 16 KB each, 64 KB total
    __shared__ ushort_t sAl[128 * 64];
    __shared__ ushort_t sBh[128 * 64];
    __shared__ ushort_t sBl[128 * 64];

    const int tid = threadIdx.x;
    const int wave = tid >> 6, lane = tid & 63;
    const int col = lane & 15, quad = lane >> 4;
    const int wm = wave >> 1, wn = wave & 1;
    const int m0 = blockIdx.y * 128, n0 = blockIdx.x * 128;

    f32x4 acc[4][4];
#pragma unroll
    for (int i = 0; i < 4; ++i)
#pragma unroll
        for (int j = 0; j < 4; ++j) acc[i][j] = (f32x4){0.f, 0.f, 0.f, 0.f};

    for (int k0 = 0; k0 < KD; k0 += 64) {
        // stage: 128 rows x 8 16B-slots per matrix = 1024 slots, 4/thread.
        // LDS linear in slot order; global k-block XOR-swizzled by row.
#pragma unroll
        for (int p = 0; p < 4; ++p) {
            int s   = p * 256 + wave * 64 + lane;
            int row = s >> 3, j = s & 7;
            int kb  = j ^ (row & 7);                  // swizzle involution
            int lo  = (p * 256 + wave * 64) * 8;      // wave-uniform ushort off
            size_t ga = (size_t)(m0 + row) * KD + k0 + kb * 8;
            size_t gb = (size_t)(n0 + row) * KD + k0 + kb * 8;
            gload_lds16(Ah + ga, sAh + lo);
            gload_lds16(Bh + gb, sBh + lo);
            if (terms3) {
                gload_lds16(Al + ga, sAl + lo);
                gload_lds16(Bl + gb, sBl + lo);
            }
        }
        __syncthreads();

#pragma unroll
        for (int kk = 0; kk < 2; ++kk) {
            bf16x8 fah[4], fal[4], fbh[4], fbl[4];
            const int sw = (kk * 4 + quad) ^ (col & 7);   // swizzled 16B slot
#pragma unroll
            for (int j = 0; j < 4; ++j) {
                int ra = (wm * 64 + j * 16 + col) * 64 + sw * 8;
                int rb = (wn * 64 + j * 16 + col) * 64 + sw * 8;
                fah[j] = *(const bf16x8*)&sAh[ra];
                fbh[j] = *(const bf16x8*)&sBh[rb];
                if (terms3) {
                    fal[j] = *(const bf16x8*)&sAl[ra];
                    fbl[j] = *(const bf16x8*)&sBl[rb];
                }
            }
#pragma unroll
            for (int i = 0; i < 4; ++i) {
                if (terms3) {
#pragma unroll
                    for (int j = 0; j < 4; ++j) {
                        acc[i][j] = MFMA32(fah[i], fbh[j], acc[i][j]);
                        acc[i][j] = MFMA32(fah[i], fbl[j], acc[i][j]);
                        acc[i][j] = MFMA32(fal[i], fbh[j], acc[i][j]);
                    }
                } else {
#pragma unroll
                    for (int j = 0; j < 4; ++j)
                        acc[i][j] = MFMA32(fah[i], fbh[j], acc[i][j]);
                }
            }
        }
        __syncthreads();
    }

    // ---- epilogues (C/D: row m = quad*4+reg, col n = lane&15) ----
    if (epi <= 1) {
        ushort_t* OH = (epi == 0) ? OQh : OKh;
        ushort_t* OL = (epi == 0) ? OQl : OKl;
#pragma unroll
        for (int i = 0; i < 4; ++i) {
            int m = m0 + wm * 64 + i * 16 + quad * 4;
#pragma unroll
            for (int j = 0; j < 4; ++j) {
                int n = n0 + wn * 64 + j * 16 + col;
#pragma unroll
                for (int r = 0; r < 4; ++r) {
                    float v = acc[i][j][r];
                    ushort_t hv = f2bf_rn(v);
                    size_t off = (size_t)(m + r) * KD + n;
                    OH[off] = hv;
                    OL[off] = f2bf_rn(v - bf2f(hv));
                }
            }
        }
    } else if (epi == 2) {
#pragma unroll
        for (int i = 0; i < 4; ++i) {
            int m = m0 + wm * 64 + i * 16 + quad * 4;
            int bb = m >> 11, t = m & (TS - 1);
#pragma unroll
            for (int j = 0; j < 4; ++j) {
                int n = n0 + wn * 64 + j * 16 + col;
                int hh = n >> 6, d = n & 63;
                ushort4 pk = pk4_bf(acc[i][j][0], acc[i][j][1], acc[i][j][2], acc[i][j][3]);
                *(ushort4*)(OVt + ((size_t)(bb * NH + hh) * SD + d) * TS + t) = pk;
            }
        }
    } else {
#pragma unroll
        for (int i = 0; i < 4; ++i) {
            int m = m0 + wm * 64 + i * 16 + quad * 4;
#pragma unroll
            for (int j = 0; j < 4; ++j) {
                int n = n0 + wn * 64 + j * 16 + col;
                float bj = bias[n];
#pragma unroll
                for (int r = 0; r < 4; ++r)
                    OF[(size_t)(m + r) * KD + n] = acc[i][j][r] + bj;
            }
        }
    }
}

// ---------------------------------------------------------------------------
// MFMA flash attention — round-5 structure (paired K-tiles, full-K PV MFMAs)
// + T5 s_setprio(1) around the MFMA clusters. Mechanism: 2 resident blocks
// per CU run at different phases (barrier-synced within a block only);
// boosting MFMA-cluster priority lets the compute-phase block win issue
// slots over the staging/softmax-phase block (m191: +4-7% attn; null only
// on lockstep single-block GEMM, so gemm_bf16 is left untouched).
// ---------------------------------------------------------------------------
__global__ __launch_bounds__(256, 2)
void attn_mfma(const ushort_t* __restrict__ QH, const ushort_t* __restrict__ QL,
               const ushort_t* __restrict__ KH, const ushort_t* __restrict__ KL,
               const ushort_t* __restrict__ VT, const int* __restrict__ mask,
               ushort_t* __restrict__ YH)
{
    const int bh = blockIdx.x;       // 0..31  (fastest dim -> pins XCD = bh%8)
    const int qt = blockIdx.y;       // 0..31
    const int h  = bh & (NH - 1);
    const int b  = bh >> 4;

    const int tid  = threadIdx.x;
    const int wave = tid >> 6;
    const int lane = tid & 63;
    const int col  = lane & 15;
    const int quad = lane >> 4;

    // 48 KB: two 24 KB tile buffers (KH 8K | KL 8K | VT 8K each), both
    // consumed per iteration; first 16 KB reused for the O-reduce.
    __shared__ ushort_t smem[24576];
    ushort_t* sKH = smem;                // [key][d] swizzled
    ushort_t* sKL = smem + 4096;
    ushort_t* sVT = smem + 8192;         // [d][key] swizzled
    const int ODD = 12288;               // ushort offset of odd-tile buffer
    __shared__ float lred[4][64];

    // ---- Q fragments, held in registers for the whole kernel ----
    bf16x8 bqh[4][2], bql[4][2];
#pragma unroll
    for (int qf = 0; qf < 4; ++qf) {
        size_t qrow = (size_t)(b * TS + qt * 64 + qf * 16 + col) * KD + h * SD;
#pragma unroll
        for (int c = 0; c < 2; ++c) {
            bqh[qf][c] = *(const bf16x8*)(QH + qrow + c * 32 + quad * 8);
            bql[qf][c] = *(const bf16x8*)(QL + qrow + c * 32 + quad * 8);
        }
    }

    // ---- hoisted staging pointers: chunk r -> {r<2: KH, r<4: KL, else VT} ----
    const int l8 = lane >> 3, l7 = lane & 7;
    const ushort_t* gp[6];
    ushort_t* ld[6];
#pragma unroll
    for (int r = 0; r < 6; ++r) {
        int cc  = (r & 1) * 4 + wave;          // chunk within its matrix (0..7)
        int row = cc * 8 + l8;                 // 0..63
        int gs  = l7 ^ (row & 7);              // XOR swizzle
        if (r < 2)      gp[r] = KH + (size_t)(b * TS + row) * KD + h * SD + gs * 8;
        else if (r < 4) gp[r] = KL + (size_t)(b * TS + row) * KD + h * SD + gs * 8;
        else            gp[r] = VT + ((size_t)bh * SD + row) * TS + gs * 8;
        ld[r] = ((r < 2) ? sKH : (r < 4) ? sKL : sVT) + cc * 512;
    }
    const int* mp = mask + b * TS + wave * 16 + quad * 4;

    float lp[4] = {0.f, 0.f, 0.f, 0.f};
    f32x4 O[4][4];                        // [dt][qf], O^T: row=d, col=q
#pragma unroll
    for (int dt = 0; dt < 4; ++dt)
#pragma unroll
        for (int qf = 0; qf < 4; ++qf) O[dt][qf] = (f32x4){0.f, 0.f, 0.f, 0.f};

    frag8 av[4], bp4[4];
#pragma unroll
    for (int i = 0; i < 4; ++i) {
        av[i].v8  = (bf16x8){0, 0, 0, 0, 0, 0, 0, 0};
        bp4[i].v8 = (bf16x8){0, 0, 0, 0, 0, 0, 0, 0};
    }

    for (int pr = 0; pr < TS / 128; ++pr) {
        // ---- stage BOTH tiles of the pair (even -> base, odd -> +ODD) ----
#pragma unroll
        for (int r = 0; r < 6; ++r) {
            gload_lds16(gp[r], ld[r]);
            gload_lds16(gp[r] + ((r < 4) ? 64 * KD : 64), ld[r] + ODD);
        }
        int4 mv0 = *(const int4*)mp;
        int4 mv1 = *(const int4*)(mp + 64);
        mp += 128;
#pragma unroll
        for (int r = 0; r < 6; ++r) gp[r] += (r < 4) ? 128 * KD : 128;
        __syncthreads();

        // ---- each half: S^T strips + exp2 -> P into bp4[].h[half] ----
#pragma unroll
        for (int half = 0; half < 2; ++half) {
            const int bo = half ? ODD : 0;
            const int4 mv = half ? mv1 : mv0;
            f32x4 sinit;
            sinit[0] = mv.x ? 0.f : -INFINITY;
            sinit[1] = mv.y ? 0.f : -INFINITY;
            sinit[2] = mv.z ? 0.f : -INFINITY;
            sinit[3] = mv.w ? 0.f : -INFINITY;

            bf16x8 akh[2], akl[2];
#pragma unroll
            for (int c = 0; c < 2; ++c) {
                int sl = (c * 4 + quad) ^ (col & 7);
                akh[c] = *(const bf16x8*)&sKH[bo + ((wave * 16 + col) * 8 + sl) * 8];
                akl[c] = *(const bf16x8*)&sKL[bo + ((wave * 16 + col) * 8 + sl) * 8];
            }
#pragma unroll
            for (int qf = 0; qf < 4; ++qf) {
                f32x4 s1 = sinit;
                f32x4 s2 = (f32x4){0.f, 0.f, 0.f, 0.f};
                __builtin_amdgcn_s_setprio(1);
                s1 = MFMA32(akh[0], bqh[qf][0], s1);
                s2 = MFMA32(akl[0], bqh[qf][0], s2);
                s2 = MFMA32(akh[0], bql[qf][0], s2);
                s1 = MFMA32(akh[1], bqh[qf][1], s1);
                s2 = MFMA32(akl[1], bqh[qf][1], s2);
                s2 = MFMA32(akh[1], bql[qf][1], s2);
                __builtin_amdgcn_s_setprio(0);
                float p0 = fexp2(s1[0] + s2[0]);
                float p1 = fexp2(s1[1] + s2[1]);
                float p2 = fexp2(s1[2] + s2[2]);
                float p3 = fexp2(s1[3] + s2[3]);
                lp[qf] += (p0 + p1) + (p2 + p3);
                union { ushort4 u4; bf16x4 v4; } pk;
                pk.u4 = pk4_bf(p0, p1, p2, p3);
                bp4[qf].h[half] = pk.v4;
            }
        }

        // ---- V^T fragments: h[0] even tile, h[1] odd tile ----
#pragma unroll
        for (int dt = 0; dt < 4; ++dt) {
            int sl = (wave * 2 + (quad >> 1)) ^ (col & 7);
            int so = ((dt * 16 + col) * 8 + sl) * 8 + (quad & 1) * 4;
            av[dt].h[0] = *(const bf16x4*)&sVT[so];
            av[dt].h[1] = *(const bf16x4*)&sVT[ODD + so];
        }

        // ---- O^T += V^T x P^T, full-K MFMA (V0*P0 + V1*P1 fused) ----
        __builtin_amdgcn_s_setprio(1);
#pragma unroll
        for (int dt = 0; dt < 4; ++dt)
#pragma unroll
            for (int qf = 0; qf < 4; ++qf)
                O[dt][qf] = MFMA32(av[dt].v8, bp4[qf].v8, O[dt][qf]);
        __builtin_amdgcn_s_setprio(0);

        __syncthreads();
    }

    // ---- l: reduce over quads, publish per wave ----
#pragma unroll
    for (int qf = 0; qf < 4; ++qf) {
        float v = lp[qf];
        v += __shfl_xor(v, 16);
        v += __shfl_xor(v, 32);
        if (lane < 16) lred[wave][qf * 16 + lane] = v;
    }

    // ---- staged O-reduce through 16 KB of LDS (3 rounds) ----
    float* Of = (float*)smem;
#pragma unroll
    for (int w = 1; w < 4; ++w) {
        __syncthreads();
        if (wave == w) {
#pragma unroll
            for (int dt = 0; dt < 4; ++dt)
#pragma unroll
                for (int qf = 0; qf < 4; ++qf)
                    *(f32x4*)&Of[((dt * 4 + qf) * 64 + lane) * 4] = O[dt][qf];
        }
        __syncthreads();
        if (wave == 0) {
#pragma unroll
            for (int dt = 0; dt < 4; ++dt)
#pragma unroll
                for (int qf = 0; qf < 4; ++qf)
                    O[dt][qf] += *(const f32x4*)&Of[((dt * 4 + qf) * 64 + lane) * 4];
        }
    }
    if (wave == 0) {
        float linv[4];
#pragma unroll
        for (int qf = 0; qf < 4; ++qf) {
            int q = qf * 16 + col;
            linv[qf] = 1.f / (lred[0][q] + lred[1][q] + lred[2][q] + lred[3][q]);
        }
#pragma unroll
        for (int dt = 0; dt < 4; ++dt)
#pragma unroll
            for (int qf = 0; qf < 4; ++qf) {
                ushort4 pk = pk4_bf(O[dt][qf][0] * linv[qf], O[dt][qf][1] * linv[qf],
                                    O[dt][qf][2] * linv[qf], O[dt][qf][3] * linv[qf]);
                *(ushort4*)(YH + (size_t)(b * TS + qt * 64 + qf * 16 + col) * KD +
                            h * SD + dt * 16 + quad * 4) = pk;
            }
    }
}

// ---------------------------------------------------------------------------
extern "C" void kernel_launch(void* const* d_in, const int* in_sizes, int n_in,
                              void* d_out, int out_size, void* d_ws, size_t ws_size,
                              hipStream_t stream) {
    const float* x    = (const float*)d_in[0];
    const int*   mask = (const int*)d_in[1];
    const float* Wk   = (const float*)d_in[2];
    const float* Wq   = (const float*)d_in[3];
    const float* Wv   = (const float*)d_in[4];
    const float* Wu   = (const float*)d_in[5];
    const float* bu   = (const float*)d_in[6];
    float* out = (float*)d_out;

    char* w = (char*)d_ws;
    const size_t M1 = (size_t)1 << 20;
    // workspace plan (60 MB peak; VT lives in d_out until the U gemm):
    ushort_t* XH  = (ushort_t*)(w);              // [0,8M)
    ushort_t* XL  = (ushort_t*)(w + 8  * M1);    // [8,16M)
    ushort_t* WqH = (ushort_t*)(w + 16 * M1);
    ushort_t* WqL = (ushort_t*)(w + 18 * M1);
    ushort_t* WkH = (ushort_t*)(w + 20 * M1);
    ushort_t* WkL = (ushort_t*)(w + 22 * M1);
    ushort_t* WvH = (ushort_t*)(w + 24 * M1);    // [24,26M)
    ushort_t* QHb = (ushort_t*)(w + 26 * M1);    // [26,34M)
    ushort_t* QLb = (ushort_t*)(w + 34 * M1);
    ushort_t* KHb = (ushort_t*)(w + 42 * M1);
    ushort_t* KLb = (ushort_t*)(w + 50 * M1);    // ..58M
    ushort_t* WuH = (ushort_t*)(w + 58 * M1);    // [58,60M)
    ushort_t* VTb = (ushort_t*)d_out;            // 8 MB scratch in d_out
    ushort_t* YHb = (ushort_t*)(w);              // over XH (dead after QKV)

    dim3 blk(256);
    conv_all<<<dim3(1024, 8), blk, 0, stream>>>(x, Wq, Wk, Wv, Wu,
                                                XH, XL, WqH, WqL, WkH, WkL, WvH, WuH);
    // fused Q,K,V projections: 128x128 tiles -> 32x8x3 = 768 blocks
    gemm_bf16<<<dim3(8, 32, 3), blk, 0, stream>>>(XH, XL, WqH, WqL, WkH, WkL, WvH, WuH,
                                                  QHb, QLb, KHb, KLb, VTb, nullptr,
                                                  nullptr, 0);
    // attention: grid(bh, qt) so each (b,h)'s 32 blocks share one XCD's L2
    attn_mfma<<<dim3(NH * 2, 32), blk, 0, stream>>>(QHb, QLb, KHb, KLb, VTb, mask, YHb);
    // output projection + bias: 128x128 tiles -> 256 blocks
    gemm_bf16<<<dim3(8, 32, 1), blk, 0, stream>>>(YHb, nullptr, WqH, WqL, WkH, WkL, WvH, WuH,
                                                  nullptr, nullptr, nullptr, nullptr, nullptr,
                                                  out, bu, 3);
}